// Round 1
// baseline (2383.689 us; speedup 1.0000x reference)
//
#include <hip/hip_runtime.h>
#include <hip/hip_bf16.h>
#include <math.h>

// Problem constants
// B=32, N=1024, D=H=E=C=256, K_top=128, TEMP=0.1, EPS=1e-15

// ---------------------------------------------------------------------------
// deg: recip[b*N+n] = 1 / max(sum_m adj[b,n,m], 1.0)
// one wave per row, 4 rows per block
__global__ __launch_bounds__(256) void deg_kernel(const float* __restrict__ adj,
                                                  float* __restrict__ recip) {
    int tid  = threadIdx.x;
    int lane = tid & 63;
    int wave = tid >> 6;
    long long row = (long long)blockIdx.x * 4 + wave;   // 0..32767
    const float* a = adj + row * 1024;
    float ssum = 0.f;
#pragma unroll
    for (int i = 0; i < 4; ++i) {
        float4 v = *(const float4*)(a + lane * 4 + i * 256);
        ssum += v.x + v.y + v.z + v.w;
    }
#pragma unroll
    for (int off = 32; off > 0; off >>= 1) ssum += __shfl_down(ssum, off, 64);
    if (lane == 0) recip[row] = 1.0f / fmaxf(ssum, 1.0f);
}

// ---------------------------------------------------------------------------
// Generic tiled GEMM: C[M,N] = op(A) @ B (+ C if beta) (+ bias[col]) (* rowscale[row])
// TRANS_A=false: A is M x K row-major (lda = row stride)
// TRANS_A=true : A is K x M row-major (lda = row stride)  -> computes A^T @ B
// B is K x N row-major. All of M%64==0, N%64==0, K%16==0 hold for our shapes.
template <bool TRANS_A>
__global__ __launch_bounds__(256) void gemm_tiled(
    const float* __restrict__ A, int lda, long long sA,
    const float* __restrict__ B, int ldb, long long sB,
    float* __restrict__ C, int ldc, long long sC,
    int M, int N, int K, int beta,
    const float* __restrict__ bias,
    const float* __restrict__ rowscale, long long sRS) {
    __shared__ float As[16][68];
    __shared__ float Bs[16][68];
    long long bz = blockIdx.z;
    A += bz * sA;
    B += bz * sB;
    C += bz * sC;
    const int rowBase = blockIdx.y * 64;
    const int colBase = blockIdx.x * 64;
    const int tid = threadIdx.x;
    const int tx = tid & 15, ty = tid >> 4;

    float acc[4][4] = {};

    for (int k0 = 0; k0 < K; k0 += 16) {
        if (TRANS_A) {
            int kk = tid >> 4, m4 = (tid & 15) * 4;
            float4 v = *(const float4*)(A + (long long)(k0 + kk) * lda + rowBase + m4);
            *(float4*)&As[kk][m4] = v;
        } else {
            int r = tid >> 2, k4 = (tid & 3) * 4;
            float4 v = *(const float4*)(A + (long long)(rowBase + r) * lda + k0 + k4);
            As[k4 + 0][r] = v.x;
            As[k4 + 1][r] = v.y;
            As[k4 + 2][r] = v.z;
            As[k4 + 3][r] = v.w;
        }
        {
            int kk = tid >> 4, n4 = (tid & 15) * 4;
            float4 v = *(const float4*)(B + (long long)(k0 + kk) * ldb + colBase + n4);
            *(float4*)&Bs[kk][n4] = v;
        }
        __syncthreads();
#pragma unroll
        for (int kk = 0; kk < 16; ++kk) {
            float4 av = *(const float4*)&As[kk][ty * 4];
            float4 bv = *(const float4*)&Bs[kk][tx * 4];
            float a_[4] = {av.x, av.y, av.z, av.w};
            float b_[4] = {bv.x, bv.y, bv.z, bv.w};
#pragma unroll
            for (int i = 0; i < 4; ++i)
#pragma unroll
                for (int j = 0; j < 4; ++j) acc[i][j] = fmaf(a_[i], b_[j], acc[i][j]);
        }
        __syncthreads();
    }

    const float* rs = rowscale ? rowscale + bz * sRS : nullptr;
#pragma unroll
    for (int i = 0; i < 4; ++i) {
        int row = rowBase + ty * 4 + i;
        float scale = rs ? rs[row] : 1.0f;
#pragma unroll
        for (int j = 0; j < 4; ++j) {
            int col = colBase + tx * 4 + j;
            long long off = (long long)row * ldc + col;
            float v = acc[i][j];
            if (beta) v += C[off];
            if (bias) v += bias[col];
            v *= scale;
            C[off] = v;
        }
    }
}

// ---------------------------------------------------------------------------
// l2-normalize each 256-row, then relu (in place). one block per row.
__global__ __launch_bounds__(256) void l2relu_kernel(float* __restrict__ buf) {
    __shared__ float red[256];
    long long row = blockIdx.x;
    int tid = threadIdx.x;
    float v = buf[row * 256 + tid];
    red[tid] = v * v;
    __syncthreads();
    for (int k = 128; k > 0; k >>= 1) {
        if (tid < k) red[tid] += red[tid + k];
        __syncthreads();
    }
    float rn = 1.0f / fmaxf(sqrtf(red[0]), 1e-12f);
    buf[row * 256 + tid] = fmaxf(v * rn, 0.0f);
}

// softmax over 256 cols, in place. one block per row.
__global__ __launch_bounds__(256) void softmax_kernel(float* __restrict__ s) {
    __shared__ float red[256];
    long long row = blockIdx.x;
    int tid = threadIdx.x;
    float v = s[row * 256 + tid];
    red[tid] = v;
    __syncthreads();
    for (int k = 128; k > 0; k >>= 1) {
        if (tid < k) red[tid] = fmaxf(red[tid], red[tid + k]);
        __syncthreads();
    }
    float m = red[0];
    __syncthreads();
    float e = expf(v - m);
    red[tid] = e;
    __syncthreads();
    for (int k = 128; k > 0; k >>= 1) {
        if (tid < k) red[tid] += red[tid + k];
        __syncthreads();
    }
    s[row * 256 + tid] = e / red[0];
}

// scores[b,c] = sum_n s[b,n,c]   (partial chunks of 32 n, atomic accumulate)
__global__ __launch_bounds__(256) void scores_kernel(const float* __restrict__ s,
                                                     float* __restrict__ scores) {
    int b = blockIdx.x, chunk = blockIdx.y, c = threadIdx.x;
    const float* base = s + (long long)b * 262144 + (long long)chunk * 32 * 256 + c;
    float acc = 0.f;
#pragma unroll
    for (int i = 0; i < 32; ++i) acc += base[i * 256];
    atomicAdd(&scores[b * 256 + c], acc);
}

// thresh[b] = 128th largest of scores[b, :]  (rank by counting, stable ties)
__global__ __launch_bounds__(256) void topk_kernel(const float* __restrict__ scores,
                                                   float* __restrict__ thresh) {
    __shared__ float vals[256];
    int b = blockIdx.x, tid = threadIdx.x;
    float v = scores[b * 256 + tid];
    vals[tid] = v;
    __syncthreads();
    int rank = 0;
    for (int j = 0; j < 256; ++j) {
        float u = vals[j];
        rank += (u > v) || (u == v && j < tid);
    }
    if (rank == 127) thresh[b] = v;
}

// gate[b,c] = sigmoid((scores - thresh)/TEMP)
__global__ __launch_bounds__(256) void gate_kernel(const float* __restrict__ scores,
                                                   const float* __restrict__ thresh,
                                                   float* __restrict__ gate) {
    int b = blockIdx.x, c = threadIdx.x;
    float z = (scores[b * 256 + c] - thresh[b]) * 10.0f;  // 1/TEMP
    gate[b * 256 + c] = 1.0f / (1.0f + expf(-z));
}

// s *= gate (in place) and entropy partial: sum(-s*log(s+eps))
__global__ __launch_bounds__(256) void gate_ent_kernel(float* __restrict__ s,
                                                       const float* __restrict__ gate,
                                                       float* __restrict__ accum) {
    __shared__ float red[256];
    int tid = threadIdx.x;
    long long row = blockIdx.x;  // b*N + n
    int b = blockIdx.x >> 10;
    float v = s[row * 256 + tid] * gate[b * 256 + tid];
    s[row * 256 + tid] = v;
    red[tid] = -v * logf(v + 1e-15f);
    __syncthreads();
    for (int k = 128; k > 0; k >>= 1) {
        if (tid < k) red[tid] += red[tid + k];
        __syncthreads();
    }
    if (tid == 0) atomicAdd(&accum[2], red[0]);
}

// Fused link + recon losses:
// ssT[n,m] = sum_c s[n,c]*s[m,c];  rc[n,m] = sum_c t[n,c]*s[m,c]
// accumulate (adj-ssT)^2 into accum[0], (adj-rc)^2 into accum[1]
__global__ __launch_bounds__(256) void link_recon_kernel(const float* __restrict__ s,
                                                         const float* __restrict__ t,
                                                         const float* __restrict__ adj,
                                                         float* __restrict__ accum) {
    __shared__ float Sn[16][68], Tn[16][68], Sm[16][68];
    __shared__ float r1[256], r2[256];
    long long b = blockIdx.z;
    const float* sb = s + b * 262144;
    const float* tb = t + b * 262144;
    const float* ab = adj + b * 1048576;
    int nBase = blockIdx.y * 64, mBase = blockIdx.x * 64;
    int tid = threadIdx.x, tx = tid & 15, ty = tid >> 4;
    float ass[4][4] = {}, arc[4][4] = {};
    for (int k0 = 0; k0 < 256; k0 += 16) {
        int r = tid >> 2, k4 = (tid & 3) * 4;
        float4 v1 = *(const float4*)(sb + (long long)(nBase + r) * 256 + k0 + k4);
        Sn[k4 + 0][r] = v1.x; Sn[k4 + 1][r] = v1.y; Sn[k4 + 2][r] = v1.z; Sn[k4 + 3][r] = v1.w;
        float4 v2 = *(const float4*)(tb + (long long)(nBase + r) * 256 + k0 + k4);
        Tn[k4 + 0][r] = v2.x; Tn[k4 + 1][r] = v2.y; Tn[k4 + 2][r] = v2.z; Tn[k4 + 3][r] = v2.w;
        float4 v3 = *(const float4*)(sb + (long long)(mBase + r) * 256 + k0 + k4);
        Sm[k4 + 0][r] = v3.x; Sm[k4 + 1][r] = v3.y; Sm[k4 + 2][r] = v3.z; Sm[k4 + 3][r] = v3.w;
        __syncthreads();
#pragma unroll
        for (int kk = 0; kk < 16; ++kk) {
            float4 an = *(const float4*)&Sn[kk][ty * 4];
            float4 at = *(const float4*)&Tn[kk][ty * 4];
            float4 bm = *(const float4*)&Sm[kk][tx * 4];
            float an_[4] = {an.x, an.y, an.z, an.w};
            float at_[4] = {at.x, at.y, at.z, at.w};
            float bm_[4] = {bm.x, bm.y, bm.z, bm.w};
#pragma unroll
            for (int i = 0; i < 4; ++i)
#pragma unroll
                for (int j = 0; j < 4; ++j) {
                    ass[i][j] = fmaf(an_[i], bm_[j], ass[i][j]);
                    arc[i][j] = fmaf(at_[i], bm_[j], arc[i][j]);
                }
        }
        __syncthreads();
    }
    float l1 = 0.f, l2 = 0.f;
#pragma unroll
    for (int i = 0; i < 4; ++i)
#pragma unroll
        for (int j = 0; j < 4; ++j) {
            float a = ab[(long long)(nBase + ty * 4 + i) * 1024 + mBase + tx * 4 + j];
            float d1 = a - ass[i][j];
            l1 = fmaf(d1, d1, l1);
            float d2 = a - arc[i][j];
            l2 = fmaf(d2, d2, l2);
        }
    r1[tid] = l1;
    r2[tid] = l2;
    __syncthreads();
    for (int k = 128; k > 0; k >>= 1) {
        if (tid < k) {
            r1[tid] += r1[tid + k];
            r2[tid] += r2[tid + k];
        }
        __syncthreads();
    }
    if (tid == 0) {
        atomicAdd(&accum[0], r1[0]);
        atomicAdd(&accum[1], r2[0]);
    }
}

// clu: per batch b, fro = ||sts||_F; clu_b = ||sts/max(fro,1e-12) - I/16||_F; sum into accum[3]
__global__ __launch_bounds__(256) void clu_kernel(const float* __restrict__ sts,
                                                  float* __restrict__ accum) {
    __shared__ float red[256];
    int b = blockIdx.x, tid = threadIdx.x;
    const float* p = sts + (long long)b * 65536;
    float ss = 0.f;
    for (int i = tid; i < 65536; i += 256) {
        float v = p[i];
        ss = fmaf(v, v, ss);
    }
    red[tid] = ss;
    __syncthreads();
    for (int k = 128; k > 0; k >>= 1) {
        if (tid < k) red[tid] += red[tid + k];
        __syncthreads();
    }
    float fro = fmaxf(sqrtf(red[0]), 1e-12f);
    __syncthreads();
    float acc = 0.f;
    for (int i = tid; i < 65536; i += 256) {
        float v = p[i] / fro;
        int rr = i >> 8, cc = i & 255;
        if (rr == cc) v -= 0.0625f;  // 1/sqrt(256)
        acc = fmaf(v, v, acc);
    }
    red[tid] = acc;
    __syncthreads();
    for (int k = 128; k > 0; k >>= 1) {
        if (tid < k) red[tid] += red[tid + k];
        __syncthreads();
    }
    if (tid == 0) atomicAdd(&accum[3], sqrtf(red[0]));
}

__global__ void finalize_kernel(const float* __restrict__ accum, float* __restrict__ scal) {
    if (threadIdx.x == 0 && blockIdx.x == 0) {
        const float numel = 33554432.0f;  // B*N*N
        scal[0] = sqrtf(accum[0]) / numel;  // link
        scal[1] = accum[2] / 32768.0f;      // ent   (/ B*N)
        scal[2] = accum[3] / 32.0f;         // clu   (/ B)
        scal[3] = sqrtf(accum[1]) / numel;  // recon
    }
}

// ---------------------------------------------------------------------------
extern "C" void kernel_launch(void* const* d_in, const int* in_sizes, int n_in,
                              void* d_out, int out_size, void* d_ws, size_t ws_size,
                              hipStream_t stream) {
    const float* x    = (const float*)d_in[0];   // [32,1024,256]
    const float* adj  = (const float*)d_in[1];   // [32,1024,1024]
    const float* Wr_p = (const float*)d_in[2];
    const float* br_p = (const float*)d_in[3];
    const float* Wo_p = (const float*)d_in[4];
    const float* Wl_p = (const float*)d_in[5];
    const float* bl_p = (const float*)d_in[6];
    const float* Wr_e = (const float*)d_in[7];
    const float* br_e = (const float*)d_in[8];
    const float* Wo_e = (const float*)d_in[9];
    const float* Wl_e = (const float*)d_in[10];
    const float* bl_e = (const float*)d_in[11];

    float* out    = (float*)d_out;
    float* xp     = out;              // [32,256,256]
    float* adj_p  = out + 2097152;    // [32,256,256]
    float* s      = out + 4194304;    // [32,1024,256]  (also holds s_logits pre-softmax)
    float* scal   = out + 12582912;   // link, ent, clu, recon
    float* node_x = out + 12582916;   // [32,1024,256]

    float* W      = (float*)d_ws;
    float* deg    = W;                // 32768 (recip deg)
    float* accum  = W + 32768;        // 16: [link_sq, recon_sq, ent_sum, clu_sum]
    float* scores = W + 32784;        // 8192
    float* thresh = W + 40976;        // 32
    float* gate   = W + 41008;        // 8192
    float* aggbuf = W + 49200;        // 8388608: agg -> sTa -> sts
    float* hpbuf  = aggbuf + 8388608; // 8388608: h_p -> h_e -> t

    // zero accum + scores (poisoned each call)
    hipMemsetAsync(accum, 0, (16 + 8192) * sizeof(float), stream);

    // 1) deg
    deg_kernel<<<8192, 256, 0, stream>>>(adj, deg);

    // 2) agg = (adj @ x) * recip_deg   [batched NN]
    gemm_tiled<false><<<dim3(4, 16, 32), 256, 0, stream>>>(
        adj, 1024, 1048576LL, x, 256, 262144LL, aggbuf, 256, 262144LL,
        1024, 256, 1024, 0, nullptr, deg, 1024LL);

    // 3) pool branch: h_p = l2relu(agg@Wr_p + x@Wo_p + br_p); slog = h_p@Wl_p + bl_p
    gemm_tiled<false><<<dim3(4, 512, 1), 256, 0, stream>>>(
        aggbuf, 256, 0, Wr_p, 256, 0, hpbuf, 256, 0, 32768, 256, 256, 0, nullptr, nullptr, 0);
    gemm_tiled<false><<<dim3(4, 512, 1), 256, 0, stream>>>(
        x, 256, 0, Wo_p, 256, 0, hpbuf, 256, 0, 32768, 256, 256, 1, br_p, nullptr, 0);
    l2relu_kernel<<<32768, 256, 0, stream>>>(hpbuf);
    gemm_tiled<false><<<dim3(4, 512, 1), 256, 0, stream>>>(
        hpbuf, 256, 0, Wl_p, 256, 0, s, 256, 0, 32768, 256, 256, 0, bl_p, nullptr, 0);

    // 4) embed branch: h_e (reuse hpbuf); node_x = h_e@Wl_e + bl_e
    gemm_tiled<false><<<dim3(4, 512, 1), 256, 0, stream>>>(
        aggbuf, 256, 0, Wr_e, 256, 0, hpbuf, 256, 0, 32768, 256, 256, 0, nullptr, nullptr, 0);
    gemm_tiled<false><<<dim3(4, 512, 1), 256, 0, stream>>>(
        x, 256, 0, Wo_e, 256, 0, hpbuf, 256, 0, 32768, 256, 256, 1, br_e, nullptr, 0);
    l2relu_kernel<<<32768, 256, 0, stream>>>(hpbuf);
    gemm_tiled<false><<<dim3(4, 512, 1), 256, 0, stream>>>(
        hpbuf, 256, 0, Wl_e, 256, 0, node_x, 256, 0, 32768, 256, 256, 0, bl_e, nullptr, 0);

    // 5) softmax (in place on s), scores, top-k threshold, gate, apply + entropy
    softmax_kernel<<<32768, 256, 0, stream>>>(s);
    scores_kernel<<<dim3(32, 32, 1), 256, 0, stream>>>(s, scores);
    topk_kernel<<<32, 256, 0, stream>>>(scores, thresh);
    gate_kernel<<<32, 256, 0, stream>>>(scores, thresh, gate);
    gate_ent_kernel<<<32768, 256, 0, stream>>>(s, gate, accum);

    // 6) xp = s^T @ node_x  [batched TN]
    gemm_tiled<true><<<dim3(4, 4, 32), 256, 0, stream>>>(
        s, 256, 262144LL, node_x, 256, 262144LL, xp, 256, 65536LL,
        256, 256, 1024, 0, nullptr, nullptr, 0);

    // 7) sTa = s^T @ adj -> aggbuf   [batched TN]
    gemm_tiled<true><<<dim3(16, 4, 32), 256, 0, stream>>>(
        s, 256, 262144LL, adj, 1024, 1048576LL, aggbuf, 1024, 262144LL,
        256, 1024, 1024, 0, nullptr, nullptr, 0);

    // 8) adj_p = sTa @ s   [batched NN]
    gemm_tiled<false><<<dim3(4, 4, 32), 256, 0, stream>>>(
        aggbuf, 1024, 262144LL, s, 256, 262144LL, adj_p, 256, 65536LL,
        256, 256, 1024, 0, nullptr, nullptr, 0);

    // 9) sts = s^T @ s -> aggbuf (reuse; sTa dead)   [batched TN]
    gemm_tiled<true><<<dim3(4, 4, 32), 256, 0, stream>>>(
        s, 256, 262144LL, s, 256, 262144LL, aggbuf, 256, 65536LL,
        256, 256, 1024, 0, nullptr, nullptr, 0);

    // 10) t = s @ adj_p -> hpbuf   [batched NN]
    gemm_tiled<false><<<dim3(4, 16, 32), 256, 0, stream>>>(
        s, 256, 262144LL, adj_p, 256, 65536LL, hpbuf, 256, 262144LL,
        1024, 256, 256, 0, nullptr, nullptr, 0);

    // 11) fused link + recon losses
    link_recon_kernel<<<dim3(16, 16, 32), 256, 0, stream>>>(s, hpbuf, adj, accum);

    // 12) clu loss (reads sts in aggbuf)
    clu_kernel<<<32, 256, 0, stream>>>(aggbuf, accum);

    // 13) scalars
    finalize_kernel<<<1, 1, 0, stream>>>(accum, scal);
}

// Round 2
// 2030.238 us; speedup vs baseline: 1.1741x; 1.1741x over previous
//
#include <hip/hip_runtime.h>
#include <hip/hip_bf16.h>
#include <math.h>

// Problem constants: B=32, N=1024, D=H=E=C=256, K_top=128, TEMP=0.1, EPS=1e-15

// ---------------------------------------------------------------------------
// deg: recip[b*N+n] = 1 / max(sum_m adj[b,n,m], 1.0)
__global__ __launch_bounds__(256) void deg_kernel(const float* __restrict__ adj,
                                                  float* __restrict__ recip) {
    int tid  = threadIdx.x;
    int lane = tid & 63;
    int wave = tid >> 6;
    long long row = (long long)blockIdx.x * 4 + wave;   // 0..32767
    const float* a = adj + row * 1024;
    float ssum = 0.f;
#pragma unroll
    for (int i = 0; i < 4; ++i) {
        float4 v = *(const float4*)(a + lane * 4 + i * 256);
        ssum += v.x + v.y + v.z + v.w;
    }
#pragma unroll
    for (int off = 32; off > 0; off >>= 1) ssum += __shfl_down(ssum, off, 64);
    if (lane == 0) recip[row] = 1.0f / fmaxf(ssum, 1.0f);
}

// ---------------------------------------------------------------------------
// Generic tiled GEMM: C[M,N] = op(A) @ B (+ C if beta) (+ bias[col]) (* rowscale[row])
template <bool TRANS_A>
__global__ __launch_bounds__(256) void gemm_tiled(
    const float* __restrict__ A, int lda, long long sA,
    const float* __restrict__ B, int ldb, long long sB,
    float* __restrict__ C, int ldc, long long sC,
    int M, int N, int K, int beta,
    const float* __restrict__ bias,
    const float* __restrict__ rowscale, long long sRS) {
    __shared__ float As[16][68];
    __shared__ float Bs[16][68];
    long long bz = blockIdx.z;
    A += bz * sA;
    B += bz * sB;
    C += bz * sC;
    const int rowBase = blockIdx.y * 64;
    const int colBase = blockIdx.x * 64;
    const int tid = threadIdx.x;
    const int tx = tid & 15, ty = tid >> 4;

    float acc[4][4] = {};

    for (int k0 = 0; k0 < K; k0 += 16) {
        if (TRANS_A) {
            int kk = tid >> 4, m4 = (tid & 15) * 4;
            float4 v = *(const float4*)(A + (long long)(k0 + kk) * lda + rowBase + m4);
            *(float4*)&As[kk][m4] = v;
        } else {
            int r = tid >> 2, k4 = (tid & 3) * 4;
            float4 v = *(const float4*)(A + (long long)(rowBase + r) * lda + k0 + k4);
            As[k4 + 0][r] = v.x;
            As[k4 + 1][r] = v.y;
            As[k4 + 2][r] = v.z;
            As[k4 + 3][r] = v.w;
        }
        {
            int kk = tid >> 4, n4 = (tid & 15) * 4;
            float4 v = *(const float4*)(B + (long long)(k0 + kk) * ldb + colBase + n4);
            *(float4*)&Bs[kk][n4] = v;
        }
        __syncthreads();
#pragma unroll
        for (int kk = 0; kk < 16; ++kk) {
            float4 av = *(const float4*)&As[kk][ty * 4];
            float4 bv = *(const float4*)&Bs[kk][tx * 4];
            float a_[4] = {av.x, av.y, av.z, av.w};
            float b_[4] = {bv.x, bv.y, bv.z, bv.w};
#pragma unroll
            for (int i = 0; i < 4; ++i)
#pragma unroll
                for (int j = 0; j < 4; ++j) acc[i][j] = fmaf(a_[i], b_[j], acc[i][j]);
        }
        __syncthreads();
    }

    const float* rs = rowscale ? rowscale + bz * sRS : nullptr;
#pragma unroll
    for (int i = 0; i < 4; ++i) {
        int row = rowBase + ty * 4 + i;
        float scale = rs ? rs[row] : 1.0f;
#pragma unroll
        for (int j = 0; j < 4; ++j) {
            int col = colBase + tx * 4 + j;
            long long off = (long long)row * ldc + col;
            float v = acc[i][j];
            if (beta) v += C[off];
            if (bias) v += bias[col];
            v *= scale;
            C[off] = v;
        }
    }
}

// ---------------------------------------------------------------------------
__global__ __launch_bounds__(256) void l2relu_kernel(float* __restrict__ buf) {
    __shared__ float red[256];
    long long row = blockIdx.x;
    int tid = threadIdx.x;
    float v = buf[row * 256 + tid];
    red[tid] = v * v;
    __syncthreads();
    for (int k = 128; k > 0; k >>= 1) {
        if (tid < k) red[tid] += red[tid + k];
        __syncthreads();
    }
    float rn = 1.0f / fmaxf(sqrtf(red[0]), 1e-12f);
    buf[row * 256 + tid] = fmaxf(v * rn, 0.0f);
}

__global__ __launch_bounds__(256) void softmax_kernel(float* __restrict__ s) {
    __shared__ float red[256];
    long long row = blockIdx.x;
    int tid = threadIdx.x;
    float v = s[row * 256 + tid];
    red[tid] = v;
    __syncthreads();
    for (int k = 128; k > 0; k >>= 1) {
        if (tid < k) red[tid] = fmaxf(red[tid], red[tid + k]);
        __syncthreads();
    }
    float m = red[0];
    __syncthreads();
    float e = expf(v - m);
    red[tid] = e;
    __syncthreads();
    for (int k = 128; k > 0; k >>= 1) {
        if (tid < k) red[tid] += red[tid + k];
        __syncthreads();
    }
    s[row * 256 + tid] = e / red[0];
}

// scores[b,c] = sum_n s[b,n,c]  (32 chunks per b, atomics to 8192 distinct addrs, fan-in 32)
__global__ __launch_bounds__(256) void scores_kernel(const float* __restrict__ s,
                                                     float* __restrict__ scores) {
    int b = blockIdx.x, chunk = blockIdx.y, c = threadIdx.x;
    const float* base = s + (long long)b * 262144 + (long long)chunk * 32 * 256 + c;
    float acc = 0.f;
#pragma unroll
    for (int i = 0; i < 32; ++i) acc += base[i * 256];
    atomicAdd(&scores[b * 256 + c], acc);
}

__global__ __launch_bounds__(256) void topk_kernel(const float* __restrict__ scores,
                                                   float* __restrict__ thresh) {
    __shared__ float vals[256];
    int b = blockIdx.x, tid = threadIdx.x;
    float v = scores[b * 256 + tid];
    vals[tid] = v;
    __syncthreads();
    int rank = 0;
    for (int j = 0; j < 256; ++j) {
        float u = vals[j];
        rank += (u > v) || (u == v && j < tid);
    }
    if (rank == 127) thresh[b] = v;
}

__global__ __launch_bounds__(256) void gate_kernel(const float* __restrict__ scores,
                                                   const float* __restrict__ thresh,
                                                   float* __restrict__ gate) {
    int b = blockIdx.x, c = threadIdx.x;
    float z = (scores[b * 256 + c] - thresh[b]) * 10.0f;  // 1/TEMP
    gate[b * 256 + c] = 1.0f / (1.0f + expf(-z));
}

// s *= gate (in place); per-block entropy partial -> ent_part[blockIdx] (NO atomics)
__global__ __launch_bounds__(256) void gate_ent_kernel(float* __restrict__ s,
                                                       const float* __restrict__ gate,
                                                       float* __restrict__ ent_part) {
    __shared__ float red[256];
    int tid = threadIdx.x;
    long long row = blockIdx.x;  // b*N + n
    int b = blockIdx.x >> 10;
    float v = s[row * 256 + tid] * gate[b * 256 + tid];
    s[row * 256 + tid] = v;
    red[tid] = -v * logf(v + 1e-15f);
    __syncthreads();
    for (int k = 128; k > 0; k >>= 1) {
        if (tid < k) red[tid] += red[tid + k];
        __syncthreads();
    }
    if (tid == 0) ent_part[blockIdx.x] = red[0];
}

// Fused link + recon losses, per-block partials (NO atomics)
__global__ __launch_bounds__(256) void link_recon_kernel(const float* __restrict__ s,
                                                         const float* __restrict__ t,
                                                         const float* __restrict__ adj,
                                                         float* __restrict__ link_part,
                                                         float* __restrict__ recon_part) {
    __shared__ float Sn[16][68], Tn[16][68], Sm[16][68];
    __shared__ float r1[256], r2[256];
    long long b = blockIdx.z;
    const float* sb = s + b * 262144;
    const float* tb = t + b * 262144;
    const float* ab = adj + b * 1048576;
    int nBase = blockIdx.y * 64, mBase = blockIdx.x * 64;
    int tid = threadIdx.x, tx = tid & 15, ty = tid >> 4;
    float ass[4][4] = {}, arc[4][4] = {};
    for (int k0 = 0; k0 < 256; k0 += 16) {
        int r = tid >> 2, k4 = (tid & 3) * 4;
        float4 v1 = *(const float4*)(sb + (long long)(nBase + r) * 256 + k0 + k4);
        Sn[k4 + 0][r] = v1.x; Sn[k4 + 1][r] = v1.y; Sn[k4 + 2][r] = v1.z; Sn[k4 + 3][r] = v1.w;
        float4 v2 = *(const float4*)(tb + (long long)(nBase + r) * 256 + k0 + k4);
        Tn[k4 + 0][r] = v2.x; Tn[k4 + 1][r] = v2.y; Tn[k4 + 2][r] = v2.z; Tn[k4 + 3][r] = v2.w;
        float4 v3 = *(const float4*)(sb + (long long)(mBase + r) * 256 + k0 + k4);
        Sm[k4 + 0][r] = v3.x; Sm[k4 + 1][r] = v3.y; Sm[k4 + 2][r] = v3.z; Sm[k4 + 3][r] = v3.w;
        __syncthreads();
#pragma unroll
        for (int kk = 0; kk < 16; ++kk) {
            float4 an = *(const float4*)&Sn[kk][ty * 4];
            float4 at = *(const float4*)&Tn[kk][ty * 4];
            float4 bm = *(const float4*)&Sm[kk][tx * 4];
            float an_[4] = {an.x, an.y, an.z, an.w};
            float at_[4] = {at.x, at.y, at.z, at.w};
            float bm_[4] = {bm.x, bm.y, bm.z, bm.w};
#pragma unroll
            for (int i = 0; i < 4; ++i)
#pragma unroll
                for (int j = 0; j < 4; ++j) {
                    ass[i][j] = fmaf(an_[i], bm_[j], ass[i][j]);
                    arc[i][j] = fmaf(at_[i], bm_[j], arc[i][j]);
                }
        }
        __syncthreads();
    }
    float l1 = 0.f, l2 = 0.f;
#pragma unroll
    for (int i = 0; i < 4; ++i)
#pragma unroll
        for (int j = 0; j < 4; ++j) {
            float a = ab[(long long)(nBase + ty * 4 + i) * 1024 + mBase + tx * 4 + j];
            float d1 = a - ass[i][j];
            l1 = fmaf(d1, d1, l1);
            float d2 = a - arc[i][j];
            l2 = fmaf(d2, d2, l2);
        }
    r1[tid] = l1;
    r2[tid] = l2;
    __syncthreads();
    for (int k = 128; k > 0; k >>= 1) {
        if (tid < k) {
            r1[tid] += r1[tid + k];
            r2[tid] += r2[tid + k];
        }
        __syncthreads();
    }
    if (tid == 0) {
        int bid = (int)(blockIdx.z * 256 + blockIdx.y * 16 + blockIdx.x);
        link_part[bid] = r1[0];
        recon_part[bid] = r2[0];
    }
}

// clu: per batch b -> clu_part[b]  (NO atomics)
__global__ __launch_bounds__(256) void clu_kernel(const float* __restrict__ sts,
                                                  float* __restrict__ clu_part) {
    __shared__ float red[256];
    int b = blockIdx.x, tid = threadIdx.x;
    const float* p = sts + (long long)b * 65536;
    float ss = 0.f;
    for (int i = tid; i < 65536; i += 256) {
        float v = p[i];
        ss = fmaf(v, v, ss);
    }
    red[tid] = ss;
    __syncthreads();
    for (int k = 128; k > 0; k >>= 1) {
        if (tid < k) red[tid] += red[tid + k];
        __syncthreads();
    }
    float fro = fmaxf(sqrtf(red[0]), 1e-12f);
    __syncthreads();
    float acc = 0.f;
    for (int i = tid; i < 65536; i += 256) {
        float v = p[i] / fro;
        int rr = i >> 8, cc = i & 255;
        if (rr == cc) v -= 0.0625f;  // 1/sqrt(256)
        acc = fmaf(v, v, acc);
    }
    red[tid] = acc;
    __syncthreads();
    for (int k = 128; k > 0; k >>= 1) {
        if (tid < k) red[tid] += red[tid + k];
        __syncthreads();
    }
    if (tid == 0) clu_part[b] = sqrtf(red[0]);
}

// Final reduce of all partials -> 4 scalars. One block.
__global__ __launch_bounds__(256) void finalize_kernel(const float* __restrict__ ent_part,
                                                       const float* __restrict__ link_part,
                                                       const float* __restrict__ recon_part,
                                                       const float* __restrict__ clu_part,
                                                       float* __restrict__ scal) {
    __shared__ float red[4][256];
    int tid = threadIdx.x;
    float e = 0.f, l = 0.f, r = 0.f, c = 0.f;
    for (int i = tid; i < 32768; i += 256) e += ent_part[i];
    for (int i = tid; i < 8192; i += 256) {
        l += link_part[i];
        r += recon_part[i];
    }
    if (tid < 32) c = clu_part[tid];
    red[0][tid] = e; red[1][tid] = l; red[2][tid] = r; red[3][tid] = c;
    __syncthreads();
    for (int k = 128; k > 0; k >>= 1) {
        if (tid < k) {
#pragma unroll
            for (int q = 0; q < 4; ++q) red[q][tid] += red[q][tid + k];
        }
        __syncthreads();
    }
    if (tid == 0) {
        const float numel = 33554432.0f;  // B*N*N
        scal[0] = sqrtf(red[1][0]) / numel;  // link
        scal[1] = red[0][0] / 32768.0f;      // ent  (/ B*N)
        scal[2] = red[3][0] / 32.0f;         // clu  (/ B)
        scal[3] = sqrtf(red[2][0]) / numel;  // recon
    }
}

// ---------------------------------------------------------------------------
extern "C" void kernel_launch(void* const* d_in, const int* in_sizes, int n_in,
                              void* d_out, int out_size, void* d_ws, size_t ws_size,
                              hipStream_t stream) {
    const float* x    = (const float*)d_in[0];   // [32,1024,256]
    const float* adj  = (const float*)d_in[1];   // [32,1024,1024]
    const float* Wr_p = (const float*)d_in[2];
    const float* br_p = (const float*)d_in[3];
    const float* Wo_p = (const float*)d_in[4];
    const float* Wl_p = (const float*)d_in[5];
    const float* bl_p = (const float*)d_in[6];
    const float* Wr_e = (const float*)d_in[7];
    const float* br_e = (const float*)d_in[8];
    const float* Wo_e = (const float*)d_in[9];
    const float* Wl_e = (const float*)d_in[10];
    const float* bl_e = (const float*)d_in[11];

    float* out    = (float*)d_out;
    float* xp     = out;              // [32,256,256]
    float* adj_p  = out + 2097152;    // [32,256,256]
    float* s      = out + 4194304;    // [32,1024,256]
    float* scal   = out + 12582912;   // link, ent, clu, recon
    float* node_x = out + 12582916;   // [32,1024,256]

    float* W          = (float*)d_ws;
    float* deg        = W;                 // 32768
    float* scores     = W + 32768;         // 8192
    float* thresh     = W + 40960;         // 32
    float* gate       = W + 40992;         // 8192
    float* ent_part   = W + 49184;         // 32768
    float* link_part  = W + 81952;         // 8192
    float* recon_part = W + 90144;         // 8192
    float* clu_part   = W + 98336;         // 32
    float* aggbuf     = W + 98368;         // 8388608: agg -> sTa -> sts
    float* hpbuf      = aggbuf + 8388608;  // 8388608: h_p -> h_e -> t

    // zero scores (atomic accumulated, fan-in 32 per address)
    hipMemsetAsync(scores, 0, 8192 * sizeof(float), stream);

    // 1) deg
    deg_kernel<<<8192, 256, 0, stream>>>(adj, deg);

    // 2) agg = (adj @ x) * recip_deg   [batched NN]
    gemm_tiled<false><<<dim3(4, 16, 32), 256, 0, stream>>>(
        adj, 1024, 1048576LL, x, 256, 262144LL, aggbuf, 256, 262144LL,
        1024, 256, 1024, 0, nullptr, deg, 1024LL);

    // 3) pool branch
    gemm_tiled<false><<<dim3(4, 512, 1), 256, 0, stream>>>(
        aggbuf, 256, 0, Wr_p, 256, 0, hpbuf, 256, 0, 32768, 256, 256, 0, nullptr, nullptr, 0);
    gemm_tiled<false><<<dim3(4, 512, 1), 256, 0, stream>>>(
        x, 256, 0, Wo_p, 256, 0, hpbuf, 256, 0, 32768, 256, 256, 1, br_p, nullptr, 0);
    l2relu_kernel<<<32768, 256, 0, stream>>>(hpbuf);
    gemm_tiled<false><<<dim3(4, 512, 1), 256, 0, stream>>>(
        hpbuf, 256, 0, Wl_p, 256, 0, s, 256, 0, 32768, 256, 256, 0, bl_p, nullptr, 0);

    // 4) embed branch
    gemm_tiled<false><<<dim3(4, 512, 1), 256, 0, stream>>>(
        aggbuf, 256, 0, Wr_e, 256, 0, hpbuf, 256, 0, 32768, 256, 256, 0, nullptr, nullptr, 0);
    gemm_tiled<false><<<dim3(4, 512, 1), 256, 0, stream>>>(
        x, 256, 0, Wo_e, 256, 0, hpbuf, 256, 0, 32768, 256, 256, 1, br_e, nullptr, 0);
    l2relu_kernel<<<32768, 256, 0, stream>>>(hpbuf);
    gemm_tiled<false><<<dim3(4, 512, 1), 256, 0, stream>>>(
        hpbuf, 256, 0, Wl_e, 256, 0, node_x, 256, 0, 32768, 256, 256, 0, bl_e, nullptr, 0);

    // 5) softmax, scores, top-k, gate, apply+entropy
    softmax_kernel<<<32768, 256, 0, stream>>>(s);
    scores_kernel<<<dim3(32, 32, 1), 256, 0, stream>>>(s, scores);
    topk_kernel<<<32, 256, 0, stream>>>(scores, thresh);
    gate_kernel<<<32, 256, 0, stream>>>(scores, thresh, gate);
    gate_ent_kernel<<<32768, 256, 0, stream>>>(s, gate, ent_part);

    // 6) xp = s^T @ node_x
    gemm_tiled<true><<<dim3(4, 4, 32), 256, 0, stream>>>(
        s, 256, 262144LL, node_x, 256, 262144LL, xp, 256, 65536LL,
        256, 256, 1024, 0, nullptr, nullptr, 0);

    // 7) sTa = s^T @ adj -> aggbuf
    gemm_tiled<true><<<dim3(16, 4, 32), 256, 0, stream>>>(
        s, 256, 262144LL, adj, 1024, 1048576LL, aggbuf, 1024, 262144LL,
        256, 1024, 1024, 0, nullptr, nullptr, 0);

    // 8) adj_p = sTa @ s
    gemm_tiled<false><<<dim3(4, 4, 32), 256, 0, stream>>>(
        aggbuf, 1024, 262144LL, s, 256, 262144LL, adj_p, 256, 65536LL,
        256, 256, 1024, 0, nullptr, nullptr, 0);

    // 9) sts = s^T @ s -> aggbuf (sTa dead)
    gemm_tiled<true><<<dim3(4, 4, 32), 256, 0, stream>>>(
        s, 256, 262144LL, s, 256, 262144LL, aggbuf, 256, 65536LL,
        256, 256, 1024, 0, nullptr, nullptr, 0);

    // 10) t = s @ adj_p -> hpbuf
    gemm_tiled<false><<<dim3(4, 16, 32), 256, 0, stream>>>(
        s, 256, 262144LL, adj_p, 256, 65536LL, hpbuf, 256, 262144LL,
        1024, 256, 256, 0, nullptr, nullptr, 0);

    // 11) fused link + recon losses (partials)
    link_recon_kernel<<<dim3(16, 16, 32), 256, 0, stream>>>(s, hpbuf, adj, link_part, recon_part);

    // 12) clu loss (reads sts in aggbuf)
    clu_kernel<<<32, 256, 0, stream>>>(aggbuf, clu_part);

    // 13) reduce partials -> scalars
    finalize_kernel<<<1, 256, 0, stream>>>(ent_part, link_part, recon_part, clu_part, scal);
}

// Round 3
// 1007.427 us; speedup vs baseline: 2.3661x; 2.0153x over previous
//
#include <hip/hip_runtime.h>
#include <hip/hip_bf16.h>
#include <math.h>

// B=32, N=1024, D=H=E=C=256, K_top=128, TEMP=0.1, EPS=1e-15

typedef short bf16x8 __attribute__((ext_vector_type(8)));   // 8 bf16 raw bits (4 VGPRs)
typedef float f32x4 __attribute__((ext_vector_type(4)));

__device__ inline void gl_lds16(const void* g, void* l) {
    __builtin_amdgcn_global_load_lds(
        (const __attribute__((address_space(1))) void*)g,
        (__attribute__((address_space(3))) void*)l, 16, 0, 0);
}

__device__ inline unsigned short f2b(float f) {
    union { __hip_bfloat16 h; unsigned short u; } cv;
    cv.h = __float2bfloat16(f);
    return cv.u;
}

// ---------------------------------------------------------------------------
// Tiled convert/transpose: in fp32 [R,C] (per batch) -> optional bf16 same
// layout (outN), optional bf16 transpose [C,R] (outT), optional row sums
// (atomic, fan-in = gridDim.x) for deg. 64x64 tiles, 256 threads.
__global__ __launch_bounds__(256) void convt_kernel(
    const float* __restrict__ in, long long sIn, int ldin,
    unsigned short* __restrict__ outN, long long sN,
    unsigned short* __restrict__ outT, long long sT, int ldT,
    float* __restrict__ rowsum, long long sRS) {
    __shared__ float tile[64][65];
    __shared__ float rsum[64];
    const int tid = threadIdx.x;
    const long long bz = blockIdx.z;
    const int rowBase = blockIdx.y * 64, colBase = blockIdx.x * 64;
    const float* ip = in + bz * sIn;
    if (rowsum && tid < 64) rsum[tid] = 0.f;
    __syncthreads();
#pragma unroll
    for (int i = 0; i < 4; ++i) {
        int r = (tid >> 4) * 4 + i;
        const float4 v = *(const float4*)(ip + (long long)(rowBase + r) * ldin + colBase + (tid & 15) * 4);
        tile[r][(tid & 15) * 4 + 0] = v.x;
        tile[r][(tid & 15) * 4 + 1] = v.y;
        tile[r][(tid & 15) * 4 + 2] = v.z;
        tile[r][(tid & 15) * 4 + 3] = v.w;
        if (outN) {
            ushort4 h;
            h.x = f2b(v.x); h.y = f2b(v.y); h.z = f2b(v.z); h.w = f2b(v.w);
            *(ushort4*)(outN + bz * sN + (long long)(rowBase + r) * ldin + colBase + (tid & 15) * 4) = h;
        }
        if (rowsum) atomicAdd(&rsum[r], v.x + v.y + v.z + v.w);
    }
    __syncthreads();
    if (rowsum && tid < 64) atomicAdd(&rowsum[bz * sRS + rowBase + tid], rsum[tid]);
    if (outT) {
#pragma unroll
        for (int i = 0; i < 4; ++i) {
            int oc = (tid >> 4) * 4 + i;  // original col within tile
            ushort4 h;
            h.x = f2b(tile[(tid & 15) * 4 + 0][oc]);
            h.y = f2b(tile[(tid & 15) * 4 + 1][oc]);
            h.z = f2b(tile[(tid & 15) * 4 + 2][oc]);
            h.w = f2b(tile[(tid & 15) * 4 + 3][oc]);
            *(ushort4*)(outT + bz * sT + (long long)(colBase + oc) * ldT + rowBase + (tid & 15) * 4) = h;
        }
    }
}

// recip deg in place: d = 1/max(d,1)
__global__ __launch_bounds__(256) void recip_kernel(float* __restrict__ d) {
    int i = blockIdx.x * 256 + threadIdx.x;
    d[i] = 1.0f / fmaxf(d[i], 1.0f);
}

// 6 weight matrices [256,256] -> transposed bf16
struct WPtrs { const float* in[6]; unsigned short* out[6]; };
__global__ __launch_bounds__(256) void wconv_kernel(WPtrs wp) {
    __shared__ float tile[64][65];
    const int tid = threadIdx.x;
    const float* in = wp.in[blockIdx.z];
    unsigned short* out = wp.out[blockIdx.z];
    const int rowBase = blockIdx.y * 64, colBase = blockIdx.x * 64;
#pragma unroll
    for (int i = 0; i < 4; ++i) {
        int r = (tid >> 4) * 4 + i;
        const float4 v = *(const float4*)(in + (long long)(rowBase + r) * 256 + colBase + (tid & 15) * 4);
        tile[r][(tid & 15) * 4 + 0] = v.x;
        tile[r][(tid & 15) * 4 + 1] = v.y;
        tile[r][(tid & 15) * 4 + 2] = v.z;
        tile[r][(tid & 15) * 4 + 3] = v.w;
    }
    __syncthreads();
#pragma unroll
    for (int i = 0; i < 4; ++i) {
        int oc = (tid >> 4) * 4 + i;
        ushort4 h;
        h.x = f2b(tile[(tid & 15) * 4 + 0][oc]);
        h.y = f2b(tile[(tid & 15) * 4 + 1][oc]);
        h.z = f2b(tile[(tid & 15) * 4 + 2][oc]);
        h.w = f2b(tile[(tid & 15) * 4 + 3][oc]);
        *(ushort4*)(out + (long long)(colBase + oc) * 256 + rowBase + (tid & 15) * 4) = h;
    }
}

// ---------------------------------------------------------------------------
// MFMA GEMM: C[M,N] = A1[M,K1]·B1t[N,K1]^T (+ A2·B2t^T) (+bias[col]) (*rowscale[row])
// All operands bf16, K-contiguous. 128x128 tile, 256 threads (4 waves 2x2).
struct GemmP {
    const unsigned short* A1; long long sA1; int lda1; int K1;
    const unsigned short* B1; long long sB1; int ldb1;
    const unsigned short* A2; long long sA2; int lda2; int K2;
    const unsigned short* B2; long long sB2; int ldb2;
    float* outF; long long sF;
    unsigned short* outH; long long sH;
    int ldc;
    const float* bias;
    const float* rowscale; long long sRS;
};

__global__ __launch_bounds__(256) void gemm_mfma(GemmP p) {
    __shared__ short As[128 * 32];
    __shared__ short Bs[128 * 32];
    const int tid = threadIdx.x;
    const int wave = tid >> 6, lane = tid & 63;
    const int quad = lane >> 4, l15 = lane & 15;
    const int wm = (wave & 1) * 64, wn = (wave >> 1) * 64;
    const long long bz = blockIdx.z;
    const int rowBase = blockIdx.y * 128, colBase = blockIdx.x * 128;
    const int srow = tid >> 2;          // 0..63
    const int skg = (tid & 3) * 8;

    f32x4 acc[4][4] = {{{0.f}}};
    char* ldsA0 = (char*)As + wave * 1024;
    char* ldsA1 = (char*)As + 4096 + wave * 1024;
    char* ldsB0 = (char*)Bs + wave * 1024;
    char* ldsB1 = (char*)Bs + 4096 + wave * 1024;

    for (int pass = 0; pass < 2; ++pass) {
        const unsigned short* Aop;
        const unsigned short* Bop;
        int lda, ldb, K;
        if (pass == 0) {
            Aop = p.A1 + bz * p.sA1; Bop = p.B1 + bz * p.sB1;
            lda = p.lda1; ldb = p.ldb1; K = p.K1;
        } else {
            if (!p.A2) break;
            Aop = p.A2 + bz * p.sA2; Bop = p.B2 + bz * p.sB2;
            lda = p.lda2; ldb = p.ldb2; K = p.K2;
        }
        const unsigned short* Ab0 = Aop + (long long)(rowBase + srow) * lda + skg;
        const unsigned short* Ab1 = Aop + (long long)(rowBase + 64 + srow) * lda + skg;
        const unsigned short* Bb0 = Bop + (long long)(colBase + srow) * ldb + skg;
        const unsigned short* Bb1 = Bop + (long long)(colBase + 64 + srow) * ldb + skg;
        for (int k0 = 0; k0 < K; k0 += 32) {
            gl_lds16(Ab0 + k0, ldsA0);
            gl_lds16(Ab1 + k0, ldsA1);
            gl_lds16(Bb0 + k0, ldsB0);
            gl_lds16(Bb1 + k0, ldsB1);
            __syncthreads();
            bf16x8 af[4], bf[4];
#pragma unroll
            for (int i = 0; i < 4; ++i)
                af[i] = *(const bf16x8*)(As + (wm + i * 16 + l15) * 32 + quad * 8);
#pragma unroll
            for (int j = 0; j < 4; ++j)
                bf[j] = *(const bf16x8*)(Bs + (wn + j * 16 + l15) * 32 + quad * 8);
#pragma unroll
            for (int i = 0; i < 4; ++i)
#pragma unroll
                for (int j = 0; j < 4; ++j)
                    acc[i][j] = __builtin_amdgcn_mfma_f32_16x16x32_bf16(af[i], bf[j], acc[i][j], 0, 0, 0);
            __syncthreads();
        }
    }

    float* oF = p.outF ? p.outF + bz * p.sF : nullptr;
    unsigned short* oH = p.outH ? p.outH + bz * p.sH : nullptr;
    float bcol[4];
#pragma unroll
    for (int j = 0; j < 4; ++j)
        bcol[j] = p.bias ? p.bias[colBase + wn + j * 16 + l15] : 0.0f;
    const float* rs = p.rowscale ? p.rowscale + bz * p.sRS : nullptr;
#pragma unroll
    for (int i = 0; i < 4; ++i) {
#pragma unroll
        for (int r = 0; r < 4; ++r) {
            int row = rowBase + wm + i * 16 + quad * 4 + r;
            float sc = rs ? rs[row] : 1.0f;
            long long ro = (long long)row * p.ldc;
#pragma unroll
            for (int j = 0; j < 4; ++j) {
                int col = colBase + wn + j * 16 + l15;
                float v = (acc[i][j][r] + bcol[j]) * sc;
                if (oF) oF[ro + col] = v;
                if (oH) oH[ro + col] = f2b(v);
            }
        }
    }
}

// ---------------------------------------------------------------------------
// l2-normalize each 256-wide row then relu; bf16 in, bf16 out.
__global__ __launch_bounds__(256) void l2relu_bf_kernel(const unsigned short* __restrict__ in,
                                                        unsigned short* __restrict__ outv) {
    __shared__ float red[256];
    long long row = blockIdx.x;
    int tid = threadIdx.x;
    union { unsigned short u; __hip_bfloat16 h; } cv;
    cv.u = in[row * 256 + tid];
    float v = __bfloat162float(cv.h);
    red[tid] = v * v;
    __syncthreads();
    for (int k = 128; k > 0; k >>= 1) {
        if (tid < k) red[tid] += red[tid + k];
        __syncthreads();
    }
    float rn = 1.0f / fmaxf(sqrtf(red[0]), 1e-12f);
    outv[row * 256 + tid] = f2b(fmaxf(v * rn, 0.0f));
}

__global__ __launch_bounds__(256) void softmax_kernel(float* __restrict__ s) {
    __shared__ float red[256];
    long long row = blockIdx.x;
    int tid = threadIdx.x;
    float v = s[row * 256 + tid];
    red[tid] = v;
    __syncthreads();
    for (int k = 128; k > 0; k >>= 1) {
        if (tid < k) red[tid] = fmaxf(red[tid], red[tid + k]);
        __syncthreads();
    }
    float m = red[0];
    __syncthreads();
    float e = expf(v - m);
    red[tid] = e;
    __syncthreads();
    for (int k = 128; k > 0; k >>= 1) {
        if (tid < k) red[tid] += red[tid + k];
        __syncthreads();
    }
    s[row * 256 + tid] = e / red[0];
}

// scores[b,c] = sum_n s[b,n,c]  (atomics: 8192 addrs, fan-in 32)
__global__ __launch_bounds__(256) void scores_kernel(const float* __restrict__ s,
                                                     float* __restrict__ scores) {
    int b = blockIdx.x, chunk = blockIdx.y, c = threadIdx.x;
    const float* base = s + (long long)b * 262144 + (long long)chunk * 32 * 256 + c;
    float acc = 0.f;
#pragma unroll
    for (int i = 0; i < 32; ++i) acc += base[i * 256];
    atomicAdd(&scores[b * 256 + c], acc);
}

__global__ __launch_bounds__(256) void topk_kernel(const float* __restrict__ scores,
                                                   float* __restrict__ thresh) {
    __shared__ float vals[256];
    int b = blockIdx.x, tid = threadIdx.x;
    float v = scores[b * 256 + tid];
    vals[tid] = v;
    __syncthreads();
    int rank = 0;
    for (int j = 0; j < 256; ++j) {
        float u = vals[j];
        rank += (u > v) || (u == v && j < tid);
    }
    if (rank == 127) thresh[b] = v;
}

__global__ __launch_bounds__(256) void gate_kernel(const float* __restrict__ scores,
                                                   const float* __restrict__ thresh,
                                                   float* __restrict__ gate) {
    int b = blockIdx.x, c = threadIdx.x;
    float z = (scores[b * 256 + c] - thresh[b]) * 10.0f;  // 1/TEMP
    gate[b * 256 + c] = 1.0f / (1.0f + expf(-z));
}

// s *= gate (fp32, in place) + bf16 copy + entropy partials
__global__ __launch_bounds__(256) void gate_ent_kernel(float* __restrict__ s,
                                                       const float* __restrict__ gate,
                                                       unsigned short* __restrict__ sbf,
                                                       float* __restrict__ ent_part) {
    __shared__ float red[256];
    int tid = threadIdx.x;
    long long row = blockIdx.x;
    int b = blockIdx.x >> 10;
    float v = s[row * 256 + tid] * gate[b * 256 + tid];
    s[row * 256 + tid] = v;
    sbf[row * 256 + tid] = f2b(v);
    red[tid] = -v * logf(v + 1e-15f);
    __syncthreads();
    for (int k = 128; k > 0; k >>= 1) {
        if (tid < k) red[tid] += red[tid + k];
        __syncthreads();
    }
    if (tid == 0) ent_part[blockIdx.x] = red[0];
}

// ---------------------------------------------------------------------------
// Fused link+recon via MFMA: per 128x128 (n,m) tile compute ssT=S·S^T and
// rc=T·S^T (K=256), subtract from adj, accumulate squared diffs.
__global__ __launch_bounds__(256) void link_recon_mfma(
    const unsigned short* __restrict__ sb16, const unsigned short* __restrict__ tb16,
    const float* __restrict__ adj,
    float* __restrict__ link_part, float* __restrict__ recon_part) {
    __shared__ short Sn[128 * 32], Tn[128 * 32], Sm[128 * 32];
    __shared__ float red[2][256];
    const int tid = threadIdx.x;
    const int wave = tid >> 6, lane = tid & 63;
    const int quad = lane >> 4, l15 = lane & 15;
    const int wm = (wave & 1) * 64, wn = (wave >> 1) * 64;
    const long long bz = blockIdx.z;
    const unsigned short* S = sb16 + bz * 262144;
    const unsigned short* T = tb16 + bz * 262144;
    const float* A = adj + bz * 1048576;
    const int nBase = blockIdx.y * 128, mBase = blockIdx.x * 128;
    const int srow = tid >> 2, skg = (tid & 3) * 8;

    f32x4 as_[4][4] = {{{0.f}}}, ar_[4][4] = {{{0.f}}};
    const unsigned short* Sb0 = S + (long long)(nBase + srow) * 256 + skg;
    const unsigned short* Sb1 = S + (long long)(nBase + 64 + srow) * 256 + skg;
    const unsigned short* Tb0 = T + (long long)(nBase + srow) * 256 + skg;
    const unsigned short* Tb1 = T + (long long)(nBase + 64 + srow) * 256 + skg;
    const unsigned short* Mb0 = S + (long long)(mBase + srow) * 256 + skg;
    const unsigned short* Mb1 = S + (long long)(mBase + 64 + srow) * 256 + skg;

    for (int k0 = 0; k0 < 256; k0 += 32) {
        gl_lds16(Sb0 + k0, (char*)Sn + wave * 1024);
        gl_lds16(Sb1 + k0, (char*)Sn + 4096 + wave * 1024);
        gl_lds16(Tb0 + k0, (char*)Tn + wave * 1024);
        gl_lds16(Tb1 + k0, (char*)Tn + 4096 + wave * 1024);
        gl_lds16(Mb0 + k0, (char*)Sm + wave * 1024);
        gl_lds16(Mb1 + k0, (char*)Sm + 4096 + wave * 1024);
        __syncthreads();
        bf16x8 a1[4], a2[4], bb[4];
#pragma unroll
        for (int i = 0; i < 4; ++i) {
            a1[i] = *(const bf16x8*)(Sn + (wm + i * 16 + l15) * 32 + quad * 8);
            a2[i] = *(const bf16x8*)(Tn + (wm + i * 16 + l15) * 32 + quad * 8);
        }
#pragma unroll
        for (int j = 0; j < 4; ++j)
            bb[j] = *(const bf16x8*)(Sm + (wn + j * 16 + l15) * 32 + quad * 8);
#pragma unroll
        for (int i = 0; i < 4; ++i)
#pragma unroll
            for (int j = 0; j < 4; ++j) {
                as_[i][j] = __builtin_amdgcn_mfma_f32_16x16x32_bf16(a1[i], bb[j], as_[i][j], 0, 0, 0);
                ar_[i][j] = __builtin_amdgcn_mfma_f32_16x16x32_bf16(a2[i], bb[j], ar_[i][j], 0, 0, 0);
            }
        __syncthreads();
    }

    float l1 = 0.f, l2 = 0.f;
#pragma unroll
    for (int i = 0; i < 4; ++i)
#pragma unroll
        for (int r = 0; r < 4; ++r) {
            int row = nBase + wm + i * 16 + quad * 4 + r;
#pragma unroll
            for (int j = 0; j < 4; ++j) {
                int col = mBase + wn + j * 16 + l15;
                float a = A[(long long)row * 1024 + col];
                float d1 = a - as_[i][j][r];
                l1 = fmaf(d1, d1, l1);
                float d2 = a - ar_[i][j][r];
                l2 = fmaf(d2, d2, l2);
            }
        }
    red[0][tid] = l1;
    red[1][tid] = l2;
    __syncthreads();
    for (int k = 128; k > 0; k >>= 1) {
        if (tid < k) {
            red[0][tid] += red[0][tid + k];
            red[1][tid] += red[1][tid + k];
        }
        __syncthreads();
    }
    if (tid == 0) {
        int bid = (int)(blockIdx.z * 64 + blockIdx.y * 8 + blockIdx.x);
        link_part[bid] = red[0][0];
        recon_part[bid] = red[1][0];
    }
}

// clu per batch (reads fp32 sts)
__global__ __launch_bounds__(256) void clu_kernel(const float* __restrict__ sts,
                                                  float* __restrict__ clu_part) {
    __shared__ float red[256];
    int b = blockIdx.x, tid = threadIdx.x;
    const float* p = sts + (long long)b * 65536;
    float ss = 0.f;
    for (int i = tid; i < 65536; i += 256) {
        float v = p[i];
        ss = fmaf(v, v, ss);
    }
    red[tid] = ss;
    __syncthreads();
    for (int k = 128; k > 0; k >>= 1) {
        if (tid < k) red[tid] += red[tid + k];
        __syncthreads();
    }
    float fro = fmaxf(sqrtf(red[0]), 1e-12f);
    __syncthreads();
    float acc = 0.f;
    for (int i = tid; i < 65536; i += 256) {
        float v = p[i] / fro;
        int rr = i >> 8, cc = i & 255;
        if (rr == cc) v -= 0.0625f;  // 1/sqrt(256)
        acc = fmaf(v, v, acc);
    }
    red[tid] = acc;
    __syncthreads();
    for (int k = 128; k > 0; k >>= 1) {
        if (tid < k) red[tid] += red[tid + k];
        __syncthreads();
    }
    if (tid == 0) clu_part[b] = sqrtf(red[0]);
}

__global__ __launch_bounds__(256) void finalize_kernel(const float* __restrict__ ent_part,
                                                       const float* __restrict__ link_part,
                                                       const float* __restrict__ recon_part,
                                                       const float* __restrict__ clu_part,
                                                       float* __restrict__ scal) {
    __shared__ float red[4][256];
    int tid = threadIdx.x;
    float e = 0.f, l = 0.f, r = 0.f, c = 0.f;
    for (int i = tid; i < 32768; i += 256) e += ent_part[i];
    for (int i = tid; i < 2048; i += 256) {
        l += link_part[i];
        r += recon_part[i];
    }
    if (tid < 32) c = clu_part[tid];
    red[0][tid] = e; red[1][tid] = l; red[2][tid] = r; red[3][tid] = c;
    __syncthreads();
    for (int k = 128; k > 0; k >>= 1) {
        if (tid < k) {
#pragma unroll
            for (int q = 0; q < 4; ++q) red[q][tid] += red[q][tid + k];
        }
        __syncthreads();
    }
    if (tid == 0) {
        const float numel = 33554432.0f;  // B*N*N
        scal[0] = sqrtf(red[1][0]) / numel;  // link
        scal[1] = red[0][0] / 32768.0f;      // ent
        scal[2] = red[3][0] / 32.0f;         // clu
        scal[3] = sqrtf(red[2][0]) / numel;  // recon
    }
}

// ---------------------------------------------------------------------------
extern "C" void kernel_launch(void* const* d_in, const int* in_sizes, int n_in,
                              void* d_out, int out_size, void* d_ws, size_t ws_size,
                              hipStream_t stream) {
    const float* x    = (const float*)d_in[0];
    const float* adj  = (const float*)d_in[1];
    const float* Wr_p = (const float*)d_in[2];
    const float* br_p = (const float*)d_in[3];
    const float* Wo_p = (const float*)d_in[4];
    const float* Wl_p = (const float*)d_in[5];
    const float* bl_p = (const float*)d_in[6];
    const float* Wr_e = (const float*)d_in[7];
    const float* br_e = (const float*)d_in[8];
    const float* Wo_e = (const float*)d_in[9];
    const float* Wl_e = (const float*)d_in[10];
    const float* bl_e = (const float*)d_in[11];

    float* out    = (float*)d_out;
    float* xp     = out;              // [32,256,256]
    float* adj_p  = out + 2097152;    // [32,256,256]
    float* s      = out + 4194304;    // [32,1024,256] fp32 (logits -> softmax -> gated)
    float* scal   = out + 12582912;
    float* node_x = out + 12582916;   // [32,1024,256] fp32

    char* w = (char*)d_ws;
    float* degsum     = (float*)w; w += 32768 * 4;   // -> recip deg in place
    float* scores     = (float*)w; w += 8192 * 4;
    float* thresh     = (float*)w; w += 256 * 4;
    float* gatep      = (float*)w; w += 8192 * 4;
    float* ent_part   = (float*)w; w += 32768 * 4;
    float* link_part  = (float*)w; w += 2048 * 4;
    float* recon_part = (float*)w; w += 2048 * 4;
    float* clu_part   = (float*)w; w += 256 * 4;
    float* sts        = (float*)w; w += 2097152LL * 4;     // fp32 [32,256,256]
    unsigned short* WT   = (unsigned short*)w; w += 6LL * 65536 * 2;
    unsigned short* bufA = (unsigned short*)w; w += 33554432LL * 2;  // adj_bf -> adjT_bf
    unsigned short* bufB = (unsigned short*)w; w += 8388608LL * 2;   // x_bf -> t_bf
    unsigned short* bufC = (unsigned short*)w; w += 8388608LL * 2;   // xT_bf -> sT_bf
    unsigned short* bufD = (unsigned short*)w; w += 8388608LL * 2;   // agg_bf -> nxT_bf
    unsigned short* bufE = (unsigned short*)w; w += 8388608LL * 2;   // hp_bf (pre-norm)
    unsigned short* bufF = (unsigned short*)w; w += 8388608LL * 2;   // h_bf -> sTa_bf
    unsigned short* bufG = (unsigned short*)w; w += 8388608LL * 2;   // s_bf
    unsigned short* bufH = (unsigned short*)w; w += 2097152LL * 2;   // adjpT_bf

    // zero degsum + scores (contiguous)
    hipMemsetAsync(degsum, 0, (32768 + 8192) * sizeof(float), stream);

    // 1) adj -> adj_bf + deg row sums
    convt_kernel<<<dim3(16, 16, 32), 256, 0, stream>>>(
        adj, 1048576LL, 1024, bufA, 1048576LL, nullptr, 0, 0, degsum, 1024LL);
    recip_kernel<<<128, 256, 0, stream>>>(degsum);

    // 2) x -> x_bf + xT_bf
    convt_kernel<<<dim3(4, 16, 32), 256, 0, stream>>>(
        x, 262144LL, 256, bufB, 262144LL, bufC, 262144LL, 1024, nullptr, 0);

    // 3) weights -> transposed bf16
    WPtrs wp;
    wp.in[0] = Wr_p; wp.in[1] = Wo_p; wp.in[2] = Wl_p;
    wp.in[3] = Wr_e; wp.in[4] = Wo_e; wp.in[5] = Wl_e;
    for (int i = 0; i < 6; ++i) wp.out[i] = WT + (long long)i * 65536;
    wconv_kernel<<<dim3(4, 4, 6), 256, 0, stream>>>(wp);

    GemmP g;
    // 4) agg = (adj @ x) * deg  -> agg_bf (bufD)
    g = {};
    g.A1 = bufA; g.sA1 = 1048576; g.lda1 = 1024; g.K1 = 1024;
    g.B1 = bufC; g.sB1 = 262144; g.ldb1 = 1024;
    g.outH = bufD; g.sH = 262144; g.ldc = 256;
    g.rowscale = degsum; g.sRS = 1024;
    gemm_mfma<<<dim3(2, 8, 32), 256, 0, stream>>>(g);

    // 5) adj -> adjT_bf (bufA reused; adj_bf dead)
    convt_kernel<<<dim3(16, 16, 32), 256, 0, stream>>>(
        adj, 1048576LL, 1024, nullptr, 0, bufA, 1048576LL, 1024, nullptr, 0);

    // 6) pool pre-norm: hp = agg@Wr_p + x@Wo_p + br_p  (M=32768 folded)
    g = {};
    g.A1 = bufD; g.sA1 = 0; g.lda1 = 256; g.K1 = 256; g.B1 = WT + 0 * 65536; g.sB1 = 0; g.ldb1 = 256;
    g.A2 = bufB; g.sA2 = 0; g.lda2 = 256; g.K2 = 256; g.B2 = WT + 1 * 65536; g.sB2 = 0; g.ldb2 = 256;
    g.outH = bufE; g.sH = 0; g.ldc = 256; g.bias = br_p;
    gemm_mfma<<<dim3(2, 256, 1), 256, 0, stream>>>(g);
    l2relu_bf_kernel<<<32768, 256, 0, stream>>>(bufE, bufF);

    // 7) s_logits = h @ Wl_p + bl_p -> s (fp32, d_out)
    g = {};
    g.A1 = bufF; g.sA1 = 0; g.lda1 = 256; g.K1 = 256; g.B1 = WT + 2 * 65536; g.sB1 = 0; g.ldb1 = 256;
    g.outF = s; g.sF = 0; g.ldc = 256; g.bias = bl_p;
    gemm_mfma<<<dim3(2, 256, 1), 256, 0, stream>>>(g);

    // 8) embed branch
    g = {};
    g.A1 = bufD; g.sA1 = 0; g.lda1 = 256; g.K1 = 256; g.B1 = WT + 3 * 65536; g.sB1 = 0; g.ldb1 = 256;
    g.A2 = bufB; g.sA2 = 0; g.lda2 = 256; g.K2 = 256; g.B2 = WT + 4 * 65536; g.sB2 = 0; g.ldb2 = 256;
    g.outH = bufE; g.sH = 0; g.ldc = 256; g.bias = br_e;
    gemm_mfma<<<dim3(2, 256, 1), 256, 0, stream>>>(g);
    l2relu_bf_kernel<<<32768, 256, 0, stream>>>(bufE, bufF);
    g = {};
    g.A1 = bufF; g.sA1 = 0; g.lda1 = 256; g.K1 = 256; g.B1 = WT + 5 * 65536; g.sB1 = 0; g.ldb1 = 256;
    g.outF = node_x; g.sF = 0; g.ldc = 256; g.bias = bl_e;
    gemm_mfma<<<dim3(2, 256, 1), 256, 0, stream>>>(g);

    // 9) softmax, scores, topk, gate, apply+entropy (+s_bf)
    softmax_kernel<<<32768, 256, 0, stream>>>(s);
    scores_kernel<<<dim3(32, 32, 1), 256, 0, stream>>>(s, scores);
    topk_kernel<<<32, 256, 0, stream>>>(scores, thresh);
    gate_kernel<<<32, 256, 0, stream>>>(scores, thresh, gatep);
    gate_ent_kernel<<<32768, 256, 0, stream>>>(s, gatep, bufG, ent_part);

    // 10) transposes: s -> sT_bf (bufC), node_x -> nxT_bf (bufD)
    convt_kernel<<<dim3(4, 16, 32), 256, 0, stream>>>(
        s, 262144LL, 256, nullptr, 0, bufC, 262144LL, 1024, nullptr, 0);
    convt_kernel<<<dim3(4, 16, 32), 256, 0, stream>>>(
        node_x, 262144LL, 256, nullptr, 0, bufD, 262144LL, 1024, nullptr, 0);

    // 11) xp = sT · nxT^T  (fp32 out)
    g = {};
    g.A1 = bufC; g.sA1 = 262144; g.lda1 = 1024; g.K1 = 1024;
    g.B1 = bufD; g.sB1 = 262144; g.ldb1 = 1024;
    g.outF = xp; g.sF = 65536; g.ldc = 256;
    gemm_mfma<<<dim3(2, 2, 32), 256, 0, stream>>>(g);

    // 12) sTa = sT · adjT^T -> sTa_bf (bufF)
    g = {};
    g.A1 = bufC; g.sA1 = 262144; g.lda1 = 1024; g.K1 = 1024;
    g.B1 = bufA; g.sB1 = 1048576; g.ldb1 = 1024;
    g.outH = bufF; g.sH = 262144; g.ldc = 1024;
    gemm_mfma<<<dim3(8, 2, 32), 256, 0, stream>>>(g);

    // 13) sts = sT · sT^T (fp32 for clu)
    g = {};
    g.A1 = bufC; g.sA1 = 262144; g.lda1 = 1024; g.K1 = 1024;
    g.B1 = bufC; g.sB1 = 262144; g.ldb1 = 1024;
    g.outF = sts; g.sF = 65536; g.ldc = 256;
    gemm_mfma<<<dim3(2, 2, 32), 256, 0, stream>>>(g);

    // 14) adj_p = sTa · sT^T (fp32 out)
    g = {};
    g.A1 = bufF; g.sA1 = 262144; g.lda1 = 1024; g.K1 = 1024;
    g.B1 = bufC; g.sB1 = 262144; g.ldb1 = 1024;
    g.outF = adj_p; g.sF = 65536; g.ldc = 256;
    gemm_mfma<<<dim3(2, 2, 32), 256, 0, stream>>>(g);

    // 15) adj_p -> adjpT_bf (bufH)
    convt_kernel<<<dim3(4, 4, 32), 256, 0, stream>>>(
        adj_p, 65536LL, 256, nullptr, 0, bufH, 65536LL, 256, nullptr, 0);

    // 16) t = s · adjpT^T -> t_bf (bufB; x_bf dead)
    g = {};
    g.A1 = bufG; g.sA1 = 262144; g.lda1 = 256; g.K1 = 256;
    g.B1 = bufH; g.sB1 = 65536; g.ldb1 = 256;
    g.outH = bufB; g.sH = 262144; g.ldc = 256;
    gemm_mfma<<<dim3(2, 8, 32), 256, 0, stream>>>(g);

    // 17) fused link + recon
    link_recon_mfma<<<dim3(8, 8, 32), 256, 0, stream>>>(bufG, bufB, adj, link_part, recon_part);

    // 18) clu + finalize
    clu_kernel<<<32, 256, 0, stream>>>(sts, clu_part);
    finalize_kernel<<<1, 256, 0, stream>>>(ent_part, link_part, recon_part, clu_part, scal);
}

// Round 4
// 810.054 us; speedup vs baseline: 2.9426x; 1.2437x over previous
//
#include <hip/hip_runtime.h>
#include <hip/hip_bf16.h>
#include <math.h>

// B=32, N=1024, D=H=E=C=256, K_top=128, TEMP=0.1, EPS=1e-15

typedef short bf16x8 __attribute__((ext_vector_type(8)));   // 8 bf16 raw bits (4 VGPRs)
typedef float f32x4 __attribute__((ext_vector_type(4)));

__device__ inline void gl_lds16(const void* g, void* l) {
    __builtin_amdgcn_global_load_lds(
        (const __attribute__((address_space(1))) void*)g,
        (__attribute__((address_space(3))) void*)l, 16, 0, 0);
}

__device__ inline unsigned short f2b(float f) {
    union { __hip_bfloat16 h; unsigned short u; } cv;
    cv.h = __float2bfloat16(f);
    return cv.u;
}

// ---------------------------------------------------------------------------
// Tiled convert/transpose: fp32 [R,C] -> optional bf16 same layout (outN),
// optional bf16 transpose (outT), optional row sums (for deg).
__global__ __launch_bounds__(256) void convt_kernel(
    const float* __restrict__ in, long long sIn, int ldin,
    unsigned short* __restrict__ outN, long long sN,
    unsigned short* __restrict__ outT, long long sT, int ldT,
    float* __restrict__ rowsum, long long sRS) {
    __shared__ float tile[64][65];
    __shared__ float rsum[64];
    const int tid = threadIdx.x;
    const long long bz = blockIdx.z;
    const int rowBase = blockIdx.y * 64, colBase = blockIdx.x * 64;
    const float* ip = in + bz * sIn;
    if (rowsum && tid < 64) rsum[tid] = 0.f;
    __syncthreads();
#pragma unroll
    for (int i = 0; i < 4; ++i) {
        int r = (tid >> 4) * 4 + i;
        const float4 v = *(const float4*)(ip + (long long)(rowBase + r) * ldin + colBase + (tid & 15) * 4);
        tile[r][(tid & 15) * 4 + 0] = v.x;
        tile[r][(tid & 15) * 4 + 1] = v.y;
        tile[r][(tid & 15) * 4 + 2] = v.z;
        tile[r][(tid & 15) * 4 + 3] = v.w;
        if (outN) {
            ushort4 h;
            h.x = f2b(v.x); h.y = f2b(v.y); h.z = f2b(v.z); h.w = f2b(v.w);
            *(ushort4*)(outN + bz * sN + (long long)(rowBase + r) * ldin + colBase + (tid & 15) * 4) = h;
        }
        if (rowsum) atomicAdd(&rsum[r], v.x + v.y + v.z + v.w);
    }
    __syncthreads();
    if (rowsum && tid < 64) atomicAdd(&rowsum[bz * sRS + rowBase + tid], rsum[tid]);
    if (outT) {
#pragma unroll
        for (int i = 0; i < 4; ++i) {
            int oc = (tid >> 4) * 4 + i;
            ushort4 h;
            h.x = f2b(tile[(tid & 15) * 4 + 0][oc]);
            h.y = f2b(tile[(tid & 15) * 4 + 1][oc]);
            h.z = f2b(tile[(tid & 15) * 4 + 2][oc]);
            h.w = f2b(tile[(tid & 15) * 4 + 3][oc]);
            *(ushort4*)(outT + bz * sT + (long long)(colBase + oc) * ldT + rowBase + (tid & 15) * 4) = h;
        }
    }
}

// bf16 -> bf16 transpose, 64x64 tiles
__global__ __launch_bounds__(256) void tbf16_kernel(
    const unsigned short* __restrict__ in, long long sIn, int ldin,
    unsigned short* __restrict__ outT, long long sT, int ldT) {
    __shared__ unsigned short tile[64][68];
    const int tid = threadIdx.x;
    const long long bz = blockIdx.z;
    const int rowBase = blockIdx.y * 64, colBase = blockIdx.x * 64;
    const unsigned short* ip = in + bz * sIn;
#pragma unroll
    for (int i = 0; i < 4; ++i) {
        int r = (tid >> 4) * 4 + i, c4 = (tid & 15) * 4;
        ushort4 v = *(const ushort4*)(ip + (long long)(rowBase + r) * ldin + colBase + c4);
        tile[r][c4 + 0] = v.x; tile[r][c4 + 1] = v.y;
        tile[r][c4 + 2] = v.z; tile[r][c4 + 3] = v.w;
    }
    __syncthreads();
#pragma unroll
    for (int i = 0; i < 4; ++i) {
        int oc = (tid >> 4) * 4 + i;
        ushort4 h;
        h.x = tile[(tid & 15) * 4 + 0][oc];
        h.y = tile[(tid & 15) * 4 + 1][oc];
        h.z = tile[(tid & 15) * 4 + 2][oc];
        h.w = tile[(tid & 15) * 4 + 3][oc];
        *(ushort4*)(outT + bz * sT + (long long)(colBase + oc) * ldT + rowBase + (tid & 15) * 4) = h;
    }
}

// recip deg in place: d = 1/max(d,1)
__global__ __launch_bounds__(256) void recip_kernel(float* __restrict__ d) {
    int i = blockIdx.x * 256 + threadIdx.x;
    d[i] = 1.0f / fmaxf(d[i], 1.0f);
}

// 6 weight matrices [256,256] -> transposed bf16
struct WPtrs { const float* in[6]; unsigned short* out[6]; };
__global__ __launch_bounds__(256) void wconv_kernel(WPtrs wp) {
    __shared__ float tile[64][65];
    const int tid = threadIdx.x;
    const float* in = wp.in[blockIdx.z];
    unsigned short* out = wp.out[blockIdx.z];
    const int rowBase = blockIdx.y * 64, colBase = blockIdx.x * 64;
#pragma unroll
    for (int i = 0; i < 4; ++i) {
        int r = (tid >> 4) * 4 + i;
        const float4 v = *(const float4*)(in + (long long)(rowBase + r) * 256 + colBase + (tid & 15) * 4);
        tile[r][(tid & 15) * 4 + 0] = v.x;
        tile[r][(tid & 15) * 4 + 1] = v.y;
        tile[r][(tid & 15) * 4 + 2] = v.z;
        tile[r][(tid & 15) * 4 + 3] = v.w;
    }
    __syncthreads();
#pragma unroll
    for (int i = 0; i < 4; ++i) {
        int oc = (tid >> 4) * 4 + i;
        ushort4 h;
        h.x = f2b(tile[(tid & 15) * 4 + 0][oc]);
        h.y = f2b(tile[(tid & 15) * 4 + 1][oc]);
        h.z = f2b(tile[(tid & 15) * 4 + 2][oc]);
        h.w = f2b(tile[(tid & 15) * 4 + 3][oc]);
        *(ushort4*)(out + (long long)(colBase + oc) * 256 + rowBase + (tid & 15) * 4) = h;
    }
}

// ---------------------------------------------------------------------------
// MFMA GEMM: C[M,N] = A1[M,K1]·B1t[N,K1]^T (+ A2·B2t^T) (+bias) (*rowscale)
struct GemmP {
    const unsigned short* A1; long long sA1; int lda1; int K1;
    const unsigned short* B1; long long sB1; int ldb1;
    const unsigned short* A2; long long sA2; int lda2; int K2;
    const unsigned short* B2; long long sB2; int ldb2;
    float* outF; long long sF;
    unsigned short* outH; long long sH;
    int ldc;
    const float* bias;
    const float* rowscale; long long sRS;
};

__global__ __launch_bounds__(256) void gemm_mfma(GemmP p) {
    __shared__ short As[128 * 32];
    __shared__ short Bs[128 * 32];
    const int tid = threadIdx.x;
    const int wave = tid >> 6, lane = tid & 63;
    const int quad = lane >> 4, l15 = lane & 15;
    const int wm = (wave & 1) * 64, wn = (wave >> 1) * 64;
    const long long bz = blockIdx.z;
    const int rowBase = blockIdx.y * 128, colBase = blockIdx.x * 128;
    const int srow = tid >> 2;
    const int skg = (tid & 3) * 8;

    f32x4 acc[4][4] = {{{0.f}}};
    char* ldsA0 = (char*)As + wave * 1024;
    char* ldsA1 = (char*)As + 4096 + wave * 1024;
    char* ldsB0 = (char*)Bs + wave * 1024;
    char* ldsB1 = (char*)Bs + 4096 + wave * 1024;

    for (int pass = 0; pass < 2; ++pass) {
        const unsigned short* Aop;
        const unsigned short* Bop;
        int lda, ldb, K;
        if (pass == 0) {
            Aop = p.A1 + bz * p.sA1; Bop = p.B1 + bz * p.sB1;
            lda = p.lda1; ldb = p.ldb1; K = p.K1;
        } else {
            if (!p.A2) break;
            Aop = p.A2 + bz * p.sA2; Bop = p.B2 + bz * p.sB2;
            lda = p.lda2; ldb = p.ldb2; K = p.K2;
        }
        const unsigned short* Ab0 = Aop + (long long)(rowBase + srow) * lda + skg;
        const unsigned short* Ab1 = Aop + (long long)(rowBase + 64 + srow) * lda + skg;
        const unsigned short* Bb0 = Bop + (long long)(colBase + srow) * ldb + skg;
        const unsigned short* Bb1 = Bop + (long long)(colBase + 64 + srow) * ldb + skg;
        for (int k0 = 0; k0 < K; k0 += 32) {
            gl_lds16(Ab0 + k0, ldsA0);
            gl_lds16(Ab1 + k0, ldsA1);
            gl_lds16(Bb0 + k0, ldsB0);
            gl_lds16(Bb1 + k0, ldsB1);
            __syncthreads();
            bf16x8 af[4], bf[4];
#pragma unroll
            for (int i = 0; i < 4; ++i)
                af[i] = *(const bf16x8*)(As + (wm + i * 16 + l15) * 32 + quad * 8);
#pragma unroll
            for (int j = 0; j < 4; ++j)
                bf[j] = *(const bf16x8*)(Bs + (wn + j * 16 + l15) * 32 + quad * 8);
#pragma unroll
            for (int i = 0; i < 4; ++i)
#pragma unroll
                for (int j = 0; j < 4; ++j)
                    acc[i][j] = __builtin_amdgcn_mfma_f32_16x16x32_bf16(af[i], bf[j], acc[i][j], 0, 0, 0);
            __syncthreads();
        }
    }

    float* oF = p.outF ? p.outF + bz * p.sF : nullptr;
    unsigned short* oH = p.outH ? p.outH + bz * p.sH : nullptr;
    float bcol[4];
#pragma unroll
    for (int j = 0; j < 4; ++j)
        bcol[j] = p.bias ? p.bias[colBase + wn + j * 16 + l15] : 0.0f;
    const float* rs = p.rowscale ? p.rowscale + bz * p.sRS : nullptr;
#pragma unroll
    for (int i = 0; i < 4; ++i) {
#pragma unroll
        for (int r = 0; r < 4; ++r) {
            int row = rowBase + wm + i * 16 + quad * 4 + r;
            float sc = rs ? rs[row] : 1.0f;
            long long ro = (long long)row * p.ldc;
#pragma unroll
            for (int j = 0; j < 4; ++j) {
                int col = colBase + wn + j * 16 + l15;
                float v = (acc[i][j][r] + bcol[j]) * sc;
                if (oF) oF[ro + col] = v;
                if (oH) oH[ro + col] = f2b(v);
            }
        }
    }
}

// ---------------------------------------------------------------------------
// sts = sT · sT^T via MFMA, NO global output; reduces ssq = sum(sts^2) and
// tr = trace(sts) partials per block (for clu closed form).
__global__ __launch_bounds__(256) void sts_clu_mfma(
    const unsigned short* __restrict__ sT,
    float* __restrict__ ssq_part, float* __restrict__ tr_part) {
    __shared__ short As[128 * 32];
    __shared__ short Bs[128 * 32];
    __shared__ float red[2][256];
    const int tid = threadIdx.x;
    const int wave = tid >> 6, lane = tid & 63;
    const int quad = lane >> 4, l15 = lane & 15;
    const int wm = (wave & 1) * 64, wn = (wave >> 1) * 64;
    const long long bz = blockIdx.z;
    const unsigned short* S = sT + bz * 262144;
    const int rowBase = blockIdx.y * 128, colBase = blockIdx.x * 128;
    const int srow = tid >> 2, skg = (tid & 3) * 8;

    f32x4 acc[4][4] = {{{0.f}}};
    const unsigned short* Ab0 = S + (long long)(rowBase + srow) * 1024 + skg;
    const unsigned short* Ab1 = S + (long long)(rowBase + 64 + srow) * 1024 + skg;
    const unsigned short* Bb0 = S + (long long)(colBase + srow) * 1024 + skg;
    const unsigned short* Bb1 = S + (long long)(colBase + 64 + srow) * 1024 + skg;
    for (int k0 = 0; k0 < 1024; k0 += 32) {
        gl_lds16(Ab0 + k0, (char*)As + wave * 1024);
        gl_lds16(Ab1 + k0, (char*)As + 4096 + wave * 1024);
        gl_lds16(Bb0 + k0, (char*)Bs + wave * 1024);
        gl_lds16(Bb1 + k0, (char*)Bs + 4096 + wave * 1024);
        __syncthreads();
        bf16x8 af[4], bf[4];
#pragma unroll
        for (int i = 0; i < 4; ++i)
            af[i] = *(const bf16x8*)(As + (wm + i * 16 + l15) * 32 + quad * 8);
#pragma unroll
        for (int j = 0; j < 4; ++j)
            bf[j] = *(const bf16x8*)(Bs + (wn + j * 16 + l15) * 32 + quad * 8);
#pragma unroll
        for (int i = 0; i < 4; ++i)
#pragma unroll
            for (int j = 0; j < 4; ++j)
                acc[i][j] = __builtin_amdgcn_mfma_f32_16x16x32_bf16(af[i], bf[j], acc[i][j], 0, 0, 0);
        __syncthreads();
    }
    float ssq = 0.f, tr = 0.f;
#pragma unroll
    for (int i = 0; i < 4; ++i)
#pragma unroll
        for (int r = 0; r < 4; ++r) {
            int row = rowBase + wm + i * 16 + quad * 4 + r;
#pragma unroll
            for (int j = 0; j < 4; ++j) {
                int col = colBase + wn + j * 16 + l15;
                float v = acc[i][j][r];
                ssq = fmaf(v, v, ssq);
                if (row == col) tr += v;
            }
        }
    red[0][tid] = ssq;
    red[1][tid] = tr;
    __syncthreads();
    for (int k = 128; k > 0; k >>= 1) {
        if (tid < k) {
            red[0][tid] += red[0][tid + k];
            red[1][tid] += red[1][tid + k];
        }
        __syncthreads();
    }
    if (tid == 0) {
        int bid = (int)(blockIdx.z * 4 + blockIdx.y * 2 + blockIdx.x);
        ssq_part[bid] = red[0][0];
        tr_part[bid] = red[1][0];
    }
}

// ---------------------------------------------------------------------------
// l2-normalize each 256-wide row then relu; bf16, in-place safe.
__global__ __launch_bounds__(256) void l2relu_bf_kernel(unsigned short* __restrict__ buf) {
    __shared__ float red[256];
    long long row = blockIdx.x;
    int tid = threadIdx.x;
    union { unsigned short u; __hip_bfloat16 h; } cv;
    cv.u = buf[row * 256 + tid];
    float v = __bfloat162float(cv.h);
    red[tid] = v * v;
    __syncthreads();
    for (int k = 128; k > 0; k >>= 1) {
        if (tid < k) red[tid] += red[tid + k];
        __syncthreads();
    }
    float rn = 1.0f / fmaxf(sqrtf(red[0]), 1e-12f);
    buf[row * 256 + tid] = f2b(fmaxf(v * rn, 0.0f));
}

__global__ __launch_bounds__(256) void softmax_kernel(float* __restrict__ s) {
    __shared__ float red[256];
    long long row = blockIdx.x;
    int tid = threadIdx.x;
    float v = s[row * 256 + tid];
    red[tid] = v;
    __syncthreads();
    for (int k = 128; k > 0; k >>= 1) {
        if (tid < k) red[tid] = fmaxf(red[tid], red[tid + k]);
        __syncthreads();
    }
    float m = red[0];
    __syncthreads();
    float e = expf(v - m);
    red[tid] = e;
    __syncthreads();
    for (int k = 128; k > 0; k >>= 1) {
        if (tid < k) red[tid] += red[tid + k];
        __syncthreads();
    }
    s[row * 256 + tid] = e / red[0];
}

// scores[b,c] = sum_n s[b,n,c]
__global__ __launch_bounds__(256) void scores_kernel(const float* __restrict__ s,
                                                     float* __restrict__ scores) {
    int b = blockIdx.x, chunk = blockIdx.y, c = threadIdx.x;
    const float* base = s + (long long)b * 262144 + (long long)chunk * 32 * 256 + c;
    float acc = 0.f;
#pragma unroll
    for (int i = 0; i < 32; ++i) acc += base[i * 256];
    atomicAdd(&scores[b * 256 + c], acc);
}

__global__ __launch_bounds__(256) void topk_kernel(const float* __restrict__ scores,
                                                   float* __restrict__ thresh) {
    __shared__ float vals[256];
    int b = blockIdx.x, tid = threadIdx.x;
    float v = scores[b * 256 + tid];
    vals[tid] = v;
    __syncthreads();
    int rank = 0;
    for (int j = 0; j < 256; ++j) {
        float u = vals[j];
        rank += (u > v) || (u == v && j < tid);
    }
    if (rank == 127) thresh[b] = v;
}

__global__ __launch_bounds__(256) void gate_kernel(const float* __restrict__ scores,
                                                   const float* __restrict__ thresh,
                                                   float* __restrict__ gate) {
    int b = blockIdx.x, c = threadIdx.x;
    float z = (scores[b * 256 + c] - thresh[b]) * 10.0f;  // 1/TEMP
    gate[b * 256 + c] = 1.0f / (1.0f + expf(-z));
}

// s *= gate (fp32, in place) + bf16 copy + entropy partials
__global__ __launch_bounds__(256) void gate_ent_kernel(float* __restrict__ s,
                                                       const float* __restrict__ gate,
                                                       unsigned short* __restrict__ sbf,
                                                       float* __restrict__ ent_part) {
    __shared__ float red[256];
    int tid = threadIdx.x;
    long long row = blockIdx.x;
    int b = blockIdx.x >> 10;
    float v = s[row * 256 + tid] * gate[b * 256 + tid];
    s[row * 256 + tid] = v;
    sbf[row * 256 + tid] = f2b(v);
    red[tid] = -v * logf(v + 1e-15f);
    __syncthreads();
    for (int k = 128; k > 0; k >>= 1) {
        if (tid < k) red[tid] += red[tid + k];
        __syncthreads();
    }
    if (tid == 0) ent_part[blockIdx.x] = red[0];
}

// ---------------------------------------------------------------------------
// Fused link+recon via MFMA
__global__ __launch_bounds__(256) void link_recon_mfma(
    const unsigned short* __restrict__ sb16, const unsigned short* __restrict__ tb16,
    const float* __restrict__ adj,
    float* __restrict__ link_part, float* __restrict__ recon_part) {
    __shared__ short Sn[128 * 32], Tn[128 * 32], Sm[128 * 32];
    __shared__ float red[2][256];
    const int tid = threadIdx.x;
    const int wave = tid >> 6, lane = tid & 63;
    const int quad = lane >> 4, l15 = lane & 15;
    const int wm = (wave & 1) * 64, wn = (wave >> 1) * 64;
    const long long bz = blockIdx.z;
    const unsigned short* S = sb16 + bz * 262144;
    const unsigned short* T = tb16 + bz * 262144;
    const float* A = adj + bz * 1048576;
    const int nBase = blockIdx.y * 128, mBase = blockIdx.x * 128;
    const int srow = tid >> 2, skg = (tid & 3) * 8;

    f32x4 as_[4][4] = {{{0.f}}}, ar_[4][4] = {{{0.f}}};
    const unsigned short* Sb0 = S + (long long)(nBase + srow) * 256 + skg;
    const unsigned short* Sb1 = S + (long long)(nBase + 64 + srow) * 256 + skg;
    const unsigned short* Tb0 = T + (long long)(nBase + srow) * 256 + skg;
    const unsigned short* Tb1 = T + (long long)(nBase + 64 + srow) * 256 + skg;
    const unsigned short* Mb0 = S + (long long)(mBase + srow) * 256 + skg;
    const unsigned short* Mb1 = S + (long long)(mBase + 64 + srow) * 256 + skg;

    for (int k0 = 0; k0 < 256; k0 += 32) {
        gl_lds16(Sb0 + k0, (char*)Sn + wave * 1024);
        gl_lds16(Sb1 + k0, (char*)Sn + 4096 + wave * 1024);
        gl_lds16(Tb0 + k0, (char*)Tn + wave * 1024);
        gl_lds16(Tb1 + k0, (char*)Tn + 4096 + wave * 1024);
        gl_lds16(Mb0 + k0, (char*)Sm + wave * 1024);
        gl_lds16(Mb1 + k0, (char*)Sm + 4096 + wave * 1024);
        __syncthreads();
        bf16x8 a1[4], a2[4], bb[4];
#pragma unroll
        for (int i = 0; i < 4; ++i) {
            a1[i] = *(const bf16x8*)(Sn + (wm + i * 16 + l15) * 32 + quad * 8);
            a2[i] = *(const bf16x8*)(Tn + (wm + i * 16 + l15) * 32 + quad * 8);
        }
#pragma unroll
        for (int j = 0; j < 4; ++j)
            bb[j] = *(const bf16x8*)(Sm + (wn + j * 16 + l15) * 32 + quad * 8);
#pragma unroll
        for (int i = 0; i < 4; ++i)
#pragma unroll
            for (int j = 0; j < 4; ++j) {
                as_[i][j] = __builtin_amdgcn_mfma_f32_16x16x32_bf16(a1[i], bb[j], as_[i][j], 0, 0, 0);
                ar_[i][j] = __builtin_amdgcn_mfma_f32_16x16x32_bf16(a2[i], bb[j], ar_[i][j], 0, 0, 0);
            }
        __syncthreads();
    }

    float l1 = 0.f, l2 = 0.f;
#pragma unroll
    for (int i = 0; i < 4; ++i)
#pragma unroll
        for (int r = 0; r < 4; ++r) {
            int row = nBase + wm + i * 16 + quad * 4 + r;
#pragma unroll
            for (int j = 0; j < 4; ++j) {
                int col = mBase + wn + j * 16 + l15;
                float a = A[(long long)row * 1024 + col];
                float d1 = a - as_[i][j][r];
                l1 = fmaf(d1, d1, l1);
                float d2 = a - ar_[i][j][r];
                l2 = fmaf(d2, d2, l2);
            }
        }
    red[0][tid] = l1;
    red[1][tid] = l2;
    __syncthreads();
    for (int k = 128; k > 0; k >>= 1) {
        if (tid < k) {
            red[0][tid] += red[0][tid + k];
            red[1][tid] += red[1][tid + k];
        }
        __syncthreads();
    }
    if (tid == 0) {
        int bid = (int)(blockIdx.z * 64 + blockIdx.y * 8 + blockIdx.x);
        link_part[bid] = red[0][0];
        recon_part[bid] = red[1][0];
    }
}

__global__ __launch_bounds__(256) void finalize_kernel(const float* __restrict__ ent_part,
                                                       const float* __restrict__ link_part,
                                                       const float* __restrict__ recon_part,
                                                       const float* __restrict__ ssq_part,
                                                       const float* __restrict__ tr_part,
                                                       float* __restrict__ scal) {
    __shared__ float red[4][256];
    int tid = threadIdx.x;
    float e = 0.f, l = 0.f, r = 0.f, c = 0.f;
    for (int i = tid; i < 32768; i += 256) e += ent_part[i];
    for (int i = tid; i < 2048; i += 256) {
        l += link_part[i];
        r += recon_part[i];
    }
    if (tid < 32) {
        float ssq = 0.f, tr = 0.f;
#pragma unroll
        for (int i = 0; i < 4; ++i) {
            ssq += ssq_part[tid * 4 + i];
            tr  += tr_part[tid * 4 + i];
        }
        float fro = fmaxf(sqrtf(ssq), 1e-12f);
        float val = ssq / (fro * fro) - tr / (8.0f * fro) + 1.0f;  // ||M/fro - I/16||_F^2
        c = sqrtf(fmaxf(val, 0.0f));
    }
    red[0][tid] = e; red[1][tid] = l; red[2][tid] = r; red[3][tid] = c;
    __syncthreads();
    for (int k = 128; k > 0; k >>= 1) {
        if (tid < k) {
#pragma unroll
            for (int q = 0; q < 4; ++q) red[q][tid] += red[q][tid + k];
        }
        __syncthreads();
    }
    if (tid == 0) {
        const float numel = 33554432.0f;  // B*N*N
        scal[0] = sqrtf(red[1][0]) / numel;  // link
        scal[1] = red[0][0] / 32768.0f;      // ent
        scal[2] = red[3][0] / 32.0f;         // clu
        scal[3] = sqrtf(red[2][0]) / numel;  // recon
    }
}

// ---------------------------------------------------------------------------
extern "C" void kernel_launch(void* const* d_in, const int* in_sizes, int n_in,
                              void* d_out, int out_size, void* d_ws, size_t ws_size,
                              hipStream_t stream) {
    const float* x    = (const float*)d_in[0];
    const float* adj  = (const float*)d_in[1];
    const float* Wr_p = (const float*)d_in[2];
    const float* br_p = (const float*)d_in[3];
    const float* Wo_p = (const float*)d_in[4];
    const float* Wl_p = (const float*)d_in[5];
    const float* bl_p = (const float*)d_in[6];
    const float* Wr_e = (const float*)d_in[7];
    const float* br_e = (const float*)d_in[8];
    const float* Wo_e = (const float*)d_in[9];
    const float* Wl_e = (const float*)d_in[10];
    const float* bl_e = (const float*)d_in[11];

    float* out    = (float*)d_out;
    float* xp     = out;              // [32,256,256]
    float* adj_p  = out + 2097152;    // [32,256,256]
    float* s      = out + 4194304;    // [32,1024,256] fp32
    float* scal   = out + 12582912;
    float* node_x = out + 12582916;   // [32,1024,256] fp32

    char* w = (char*)d_ws;
    float* degsum     = (float*)w; w += 32768 * 4;
    float* scores     = (float*)w; w += 8192 * 4;
    float* thresh     = (float*)w; w += 256 * 4;
    float* gatep      = (float*)w; w += 8192 * 4;
    float* ent_part   = (float*)w; w += 32768 * 4;
    float* link_part  = (float*)w; w += 2048 * 4;
    float* recon_part = (float*)w; w += 2048 * 4;
    float* ssq_part   = (float*)w; w += 256 * 4;
    float* tr_part    = (float*)w; w += 256 * 4;
    unsigned short* WT   = (unsigned short*)w; w += 6LL * 65536 * 2;
    unsigned short* bufA = (unsigned short*)w; w += 33554432LL * 2;  // adj_bf (whole run)
    unsigned short* bufB = (unsigned short*)w; w += 8388608LL * 2;   // x_bf -> t_bf
    unsigned short* bufC = (unsigned short*)w; w += 8388608LL * 2;   // xT_bf -> sT_bf
    unsigned short* bufD = (unsigned short*)w; w += 8388608LL * 2;   // agg_bf -> nxT_bf
    unsigned short* bufE = (unsigned short*)w; w += 8388608LL * 2;   // h_bf -> aTs_bf
    unsigned short* bufF = (unsigned short*)w; w += 8388608LL * 2;   // aTsT_bf
    unsigned short* bufG = (unsigned short*)w; w += 8388608LL * 2;   // s_bf
    unsigned short* bufH = (unsigned short*)w; w += 2097152LL * 2;   // adjpT_bf

    hipMemsetAsync(degsum, 0, (32768 + 8192) * sizeof(float), stream);

    // 1) adj -> adj_bf + deg row sums (single pass over adj)
    convt_kernel<<<dim3(16, 16, 32), 256, 0, stream>>>(
        adj, 1048576LL, 1024, bufA, 1048576LL, nullptr, 0, 0, degsum, 1024LL);
    recip_kernel<<<128, 256, 0, stream>>>(degsum);

    // 2) x -> x_bf + xT_bf
    convt_kernel<<<dim3(4, 16, 32), 256, 0, stream>>>(
        x, 262144LL, 256, bufB, 262144LL, bufC, 262144LL, 1024, nullptr, 0);

    // 3) weights -> transposed bf16
    WPtrs wp;
    wp.in[0] = Wr_p; wp.in[1] = Wo_p; wp.in[2] = Wl_p;
    wp.in[3] = Wr_e; wp.in[4] = Wo_e; wp.in[5] = Wl_e;
    for (int i = 0; i < 6; ++i) wp.out[i] = WT + (long long)i * 65536;
    wconv_kernel<<<dim3(4, 4, 6), 256, 0, stream>>>(wp);

    GemmP g;
    // 4) agg = (adj @ x) * deg  -> agg_bf (bufD)
    g = {};
    g.A1 = bufA; g.sA1 = 1048576; g.lda1 = 1024; g.K1 = 1024;
    g.B1 = bufC; g.sB1 = 262144; g.ldb1 = 1024;
    g.outH = bufD; g.sH = 262144; g.ldc = 256;
    g.rowscale = degsum; g.sRS = 1024;
    gemm_mfma<<<dim3(2, 8, 32), 256, 0, stream>>>(g);

    // 5) pool pre-norm: h = agg@Wr_p + x@Wo_p + br_p -> bufE; l2relu in place
    g = {};
    g.A1 = bufD; g.sA1 = 0; g.lda1 = 256; g.K1 = 256; g.B1 = WT + 0 * 65536; g.sB1 = 0; g.ldb1 = 256;
    g.A2 = bufB; g.sA2 = 0; g.lda2 = 256; g.K2 = 256; g.B2 = WT + 1 * 65536; g.sB2 = 0; g.ldb2 = 256;
    g.outH = bufE; g.sH = 0; g.ldc = 256; g.bias = br_p;
    gemm_mfma<<<dim3(2, 256, 1), 256, 0, stream>>>(g);
    l2relu_bf_kernel<<<32768, 256, 0, stream>>>(bufE);

    // 6) s_logits = h @ Wl_p + bl_p -> s (fp32)
    g = {};
    g.A1 = bufE; g.sA1 = 0; g.lda1 = 256; g.K1 = 256; g.B1 = WT + 2 * 65536; g.sB1 = 0; g.ldb1 = 256;
    g.outF = s; g.sF = 0; g.ldc = 256; g.bias = bl_p;
    gemm_mfma<<<dim3(2, 256, 1), 256, 0, stream>>>(g);

    // 7) embed branch (reuses bufE)
    g = {};
    g.A1 = bufD; g.sA1 = 0; g.lda1 = 256; g.K1 = 256; g.B1 = WT + 3 * 65536; g.sB1 = 0; g.ldb1 = 256;
    g.A2 = bufB; g.sA2 = 0; g.lda2 = 256; g.K2 = 256; g.B2 = WT + 4 * 65536; g.sB2 = 0; g.ldb2 = 256;
    g.outH = bufE; g.sH = 0; g.ldc = 256; g.bias = br_e;
    gemm_mfma<<<dim3(2, 256, 1), 256, 0, stream>>>(g);
    l2relu_bf_kernel<<<32768, 256, 0, stream>>>(bufE);
    g = {};
    g.A1 = bufE; g.sA1 = 0; g.lda1 = 256; g.K1 = 256; g.B1 = WT + 5 * 65536; g.sB1 = 0; g.ldb1 = 256;
    g.outF = node_x; g.sF = 0; g.ldc = 256; g.bias = bl_e;
    gemm_mfma<<<dim3(2, 256, 1), 256, 0, stream>>>(g);

    // 8) softmax, scores, topk, gate, apply+entropy (+s_bf in bufG)
    softmax_kernel<<<32768, 256, 0, stream>>>(s);
    scores_kernel<<<dim3(32, 32, 1), 256, 0, stream>>>(s, scores);
    topk_kernel<<<32, 256, 0, stream>>>(scores, thresh);
    gate_kernel<<<32, 256, 0, stream>>>(scores, thresh, gatep);
    gate_ent_kernel<<<32768, 256, 0, stream>>>(s, gatep, bufG, ent_part);

    // 9) transposes: s -> sT_bf (bufC), node_x -> nxT_bf (bufD)
    convt_kernel<<<dim3(4, 16, 32), 256, 0, stream>>>(
        s, 262144LL, 256, nullptr, 0, bufC, 262144LL, 1024, nullptr, 0);
    convt_kernel<<<dim3(4, 16, 32), 256, 0, stream>>>(
        node_x, 262144LL, 256, nullptr, 0, bufD, 262144LL, 1024, nullptr, 0);

    // 10) xp = sT · nxT^T  (fp32 out)
    g = {};
    g.A1 = bufC; g.sA1 = 262144; g.lda1 = 1024; g.K1 = 1024;
    g.B1 = bufD; g.sB1 = 262144; g.ldb1 = 1024;
    g.outF = xp; g.sF = 65536; g.ldc = 256;
    gemm_mfma<<<dim3(2, 2, 32), 256, 0, stream>>>(g);

    // 11) aTs = adj · s -> bufE bf16 [1024,256]  (reuses adj_bf; no adj^T pass)
    g = {};
    g.A1 = bufA; g.sA1 = 1048576; g.lda1 = 1024; g.K1 = 1024;
    g.B1 = bufC; g.sB1 = 262144; g.ldb1 = 1024;
    g.outH = bufE; g.sH = 262144; g.ldc = 256;
    gemm_mfma<<<dim3(2, 8, 32), 256, 0, stream>>>(g);

    // 12) aTs -> aTsT_bf (bufF, [256,1024])
    tbf16_kernel<<<dim3(4, 16, 32), 256, 0, stream>>>(
        bufE, 262144LL, 256, bufF, 262144LL, 1024);

    // 13) clu partials from sts = sT·sT^T (no sts materialization)
    sts_clu_mfma<<<dim3(2, 2, 32), 256, 0, stream>>>(bufC, ssq_part, tr_part);

    // 14) adj_p = sT · aTsT^T (fp32 out)   [= s^T (adj s)]
    g = {};
    g.A1 = bufC; g.sA1 = 262144; g.lda1 = 1024; g.K1 = 1024;
    g.B1 = bufF; g.sB1 = 262144; g.ldb1 = 1024;
    g.outF = adj_p; g.sF = 65536; g.ldc = 256;
    gemm_mfma<<<dim3(2, 2, 32), 256, 0, stream>>>(g);

    // 15) adj_p -> adjpT_bf (bufH)
    convt_kernel<<<dim3(4, 4, 32), 256, 0, stream>>>(
        adj_p, 65536LL, 256, nullptr, 0, bufH, 65536LL, 256, nullptr, 0);

    // 16) t = s · adjpT^T -> t_bf (bufB)
    g = {};
    g.A1 = bufG; g.sA1 = 262144; g.lda1 = 256; g.K1 = 256;
    g.B1 = bufH; g.sB1 = 65536; g.ldb1 = 256;
    g.outH = bufB; g.sH = 262144; g.ldc = 256;
    gemm_mfma<<<dim3(2, 8, 32), 256, 0, stream>>>(g);

    // 17) fused link + recon
    link_recon_mfma<<<dim3(8, 8, 32), 256, 0, stream>>>(bufG, bufB, adj, link_part, recon_part);

    // 18) finalize (incl. clu closed form)
    finalize_kernel<<<1, 256, 0, stream>>>(ent_part, link_part, recon_part,
                                           ssq_part, tr_part, scal);
}

// Round 5
// 765.660 us; speedup vs baseline: 3.1132x; 1.0580x over previous
//
#include <hip/hip_runtime.h>
#include <hip/hip_bf16.h>
#include <math.h>

// B=32, N=1024, D=H=E=C=256, K_top=128, TEMP=0.1, EPS=1e-15

typedef short bf16x8 __attribute__((ext_vector_type(8)));   // 8 bf16 raw bits (4 VGPRs)
typedef float f32x4 __attribute__((ext_vector_type(4)));

__device__ inline void gl_lds16(const void* g, void* l) {
    __builtin_amdgcn_global_load_lds(
        (const __attribute__((address_space(1))) void*)g,
        (__attribute__((address_space(3))) void*)l, 16, 0, 0);
}

__device__ inline unsigned short f2b(float f) {
    union { __hip_bfloat16 h; unsigned short u; } cv;
    cv.h = __float2bfloat16(f);
    return cv.u;
}
__device__ inline float b2f(unsigned short u) {
    union { unsigned short u; __hip_bfloat16 h; } cv;
    cv.u = u;
    return __bfloat162float(cv.h);
}

// ---------------------------------------------------------------------------
// Tiled convert/transpose: fp32 [R,C] -> optional bf16 same layout (outN),
// optional bf16 transpose (outT), optional row sums (deg), optional sum of
// squares per block (sqpart).
__global__ __launch_bounds__(256) void convt_kernel(
    const float* __restrict__ in, long long sIn, int ldin,
    unsigned short* __restrict__ outN, long long sN,
    unsigned short* __restrict__ outT, long long sT, int ldT,
    float* __restrict__ rowsum, long long sRS,
    float* __restrict__ sqpart) {
    __shared__ float tile[64][65];
    __shared__ float rsum[64];
    __shared__ float sred[256];
    const int tid = threadIdx.x;
    const long long bz = blockIdx.z;
    const int rowBase = blockIdx.y * 64, colBase = blockIdx.x * 64;
    const float* ip = in + bz * sIn;
    if (rowsum && tid < 64) rsum[tid] = 0.f;
    __syncthreads();
    float sq = 0.f;
#pragma unroll
    for (int i = 0; i < 4; ++i) {
        int r = (tid >> 4) * 4 + i;
        const float4 v = *(const float4*)(ip + (long long)(rowBase + r) * ldin + colBase + (tid & 15) * 4);
        tile[r][(tid & 15) * 4 + 0] = v.x;
        tile[r][(tid & 15) * 4 + 1] = v.y;
        tile[r][(tid & 15) * 4 + 2] = v.z;
        tile[r][(tid & 15) * 4 + 3] = v.w;
        if (outN) {
            ushort4 h;
            h.x = f2b(v.x); h.y = f2b(v.y); h.z = f2b(v.z); h.w = f2b(v.w);
            *(ushort4*)(outN + bz * sN + (long long)(rowBase + r) * ldin + colBase + (tid & 15) * 4) = h;
        }
        if (rowsum) atomicAdd(&rsum[r], v.x + v.y + v.z + v.w);
        if (sqpart) sq += v.x * v.x + v.y * v.y + v.z * v.z + v.w * v.w;
    }
    __syncthreads();
    if (rowsum && tid < 64) atomicAdd(&rowsum[bz * sRS + rowBase + tid], rsum[tid]);
    if (outT) {
#pragma unroll
        for (int i = 0; i < 4; ++i) {
            int oc = (tid >> 4) * 4 + i;
            ushort4 h;
            h.x = f2b(tile[(tid & 15) * 4 + 0][oc]);
            h.y = f2b(tile[(tid & 15) * 4 + 1][oc]);
            h.z = f2b(tile[(tid & 15) * 4 + 2][oc]);
            h.w = f2b(tile[(tid & 15) * 4 + 3][oc]);
            *(ushort4*)(outT + bz * sT + (long long)(colBase + oc) * ldT + rowBase + (tid & 15) * 4) = h;
        }
    }
    if (sqpart) {
        sred[tid] = sq;
        __syncthreads();
        for (int k = 128; k > 0; k >>= 1) {
            if (tid < k) sred[tid] += sred[tid + k];
            __syncthreads();
        }
        if (tid == 0)
            sqpart[((long long)bz * gridDim.y + blockIdx.y) * gridDim.x + blockIdx.x] = sred[0];
    }
}

// bf16 -> bf16 transpose, 64x64 tiles
__global__ __launch_bounds__(256) void tbf16_kernel(
    const unsigned short* __restrict__ in, long long sIn, int ldin,
    unsigned short* __restrict__ outT, long long sT, int ldT) {
    __shared__ unsigned short tile[64][68];
    const int tid = threadIdx.x;
    const long long bz = blockIdx.z;
    const int rowBase = blockIdx.y * 64, colBase = blockIdx.x * 64;
    const unsigned short* ip = in + bz * sIn;
#pragma unroll
    for (int i = 0; i < 4; ++i) {
        int r = (tid >> 4) * 4 + i, c4 = (tid & 15) * 4;
        ushort4 v = *(const ushort4*)(ip + (long long)(rowBase + r) * ldin + colBase + c4);
        tile[r][c4 + 0] = v.x; tile[r][c4 + 1] = v.y;
        tile[r][c4 + 2] = v.z; tile[r][c4 + 3] = v.w;
    }
    __syncthreads();
#pragma unroll
    for (int i = 0; i < 4; ++i) {
        int oc = (tid >> 4) * 4 + i;
        ushort4 h;
        h.x = tile[(tid & 15) * 4 + 0][oc];
        h.y = tile[(tid & 15) * 4 + 1][oc];
        h.z = tile[(tid & 15) * 4 + 2][oc];
        h.w = tile[(tid & 15) * 4 + 3][oc];
        *(ushort4*)(outT + bz * sT + (long long)(colBase + oc) * ldT + rowBase + (tid & 15) * 4) = h;
    }
}

// recip deg in place: d = 1/max(d,1)
__global__ __launch_bounds__(256) void recip_kernel(float* __restrict__ d) {
    int i = blockIdx.x * 256 + threadIdx.x;
    d[i] = 1.0f / fmaxf(d[i], 1.0f);
}

// 6 weight matrices [256,256] -> transposed bf16
struct WPtrs { const float* in[6]; unsigned short* out[6]; };
__global__ __launch_bounds__(256) void wconv_kernel(WPtrs wp) {
    __shared__ float tile[64][65];
    const int tid = threadIdx.x;
    const float* in = wp.in[blockIdx.z];
    unsigned short* out = wp.out[blockIdx.z];
    const int rowBase = blockIdx.y * 64, colBase = blockIdx.x * 64;
#pragma unroll
    for (int i = 0; i < 4; ++i) {
        int r = (tid >> 4) * 4 + i;
        const float4 v = *(const float4*)(in + (long long)(rowBase + r) * 256 + colBase + (tid & 15) * 4);
        tile[r][(tid & 15) * 4 + 0] = v.x;
        tile[r][(tid & 15) * 4 + 1] = v.y;
        tile[r][(tid & 15) * 4 + 2] = v.z;
        tile[r][(tid & 15) * 4 + 3] = v.w;
    }
    __syncthreads();
#pragma unroll
    for (int i = 0; i < 4; ++i) {
        int oc = (tid >> 4) * 4 + i;
        ushort4 h;
        h.x = f2b(tile[(tid & 15) * 4 + 0][oc]);
        h.y = f2b(tile[(tid & 15) * 4 + 1][oc]);
        h.z = f2b(tile[(tid & 15) * 4 + 2][oc]);
        h.w = f2b(tile[(tid & 15) * 4 + 3][oc]);
        *(ushort4*)(out + (long long)(colBase + oc) * 256 + rowBase + (tid & 15) * 4) = h;
    }
}

// ---------------------------------------------------------------------------
// MFMA GEMM: C[M,N] = A1[M,K1]·B1t[N,K1]^T (+ A2·B2t^T) (+bias) (*rowscale)
// Optional trace-dot epilogue: dot_part[block] = sum(out ∘ dotT^T).
struct GemmP {
    const unsigned short* A1; long long sA1; int lda1; int K1;
    const unsigned short* B1; long long sB1; int ldb1;
    const unsigned short* A2; long long sA2; int lda2; int K2;
    const unsigned short* B2; long long sB2; int ldb2;
    float* outF; long long sF;
    unsigned short* outH; long long sH;
    int ldc;
    const float* bias;
    const float* rowscale; long long sRS;
    const float* dotT; long long sDot;
    float* dot_part;
};

__global__ __launch_bounds__(256) void gemm_mfma(GemmP p) {
    __shared__ short As[128 * 32];
    __shared__ short Bs[128 * 32];
    __shared__ float dred[256];
    const int tid = threadIdx.x;
    const int wave = tid >> 6, lane = tid & 63;
    const int quad = lane >> 4, l15 = lane & 15;
    const int wm = (wave & 1) * 64, wn = (wave >> 1) * 64;
    const long long bz = blockIdx.z;
    const int rowBase = blockIdx.y * 128, colBase = blockIdx.x * 128;
    const int srow = tid >> 2;
    const int skg = (tid & 3) * 8;

    f32x4 acc[4][4] = {{{0.f}}};
    char* ldsA0 = (char*)As + wave * 1024;
    char* ldsA1 = (char*)As + 4096 + wave * 1024;
    char* ldsB0 = (char*)Bs + wave * 1024;
    char* ldsB1 = (char*)Bs + 4096 + wave * 1024;

    for (int pass = 0; pass < 2; ++pass) {
        const unsigned short* Aop;
        const unsigned short* Bop;
        int lda, ldb, K;
        if (pass == 0) {
            Aop = p.A1 + bz * p.sA1; Bop = p.B1 + bz * p.sB1;
            lda = p.lda1; ldb = p.ldb1; K = p.K1;
        } else {
            if (!p.A2) break;
            Aop = p.A2 + bz * p.sA2; Bop = p.B2 + bz * p.sB2;
            lda = p.lda2; ldb = p.ldb2; K = p.K2;
        }
        const unsigned short* Ab0 = Aop + (long long)(rowBase + srow) * lda + skg;
        const unsigned short* Ab1 = Aop + (long long)(rowBase + 64 + srow) * lda + skg;
        const unsigned short* Bb0 = Bop + (long long)(colBase + srow) * ldb + skg;
        const unsigned short* Bb1 = Bop + (long long)(colBase + 64 + srow) * ldb + skg;
        for (int k0 = 0; k0 < K; k0 += 32) {
            gl_lds16(Ab0 + k0, ldsA0);
            gl_lds16(Ab1 + k0, ldsA1);
            gl_lds16(Bb0 + k0, ldsB0);
            gl_lds16(Bb1 + k0, ldsB1);
            __syncthreads();
            bf16x8 af[4], bf[4];
#pragma unroll
            for (int i = 0; i < 4; ++i)
                af[i] = *(const bf16x8*)(As + (wm + i * 16 + l15) * 32 + quad * 8);
#pragma unroll
            for (int j = 0; j < 4; ++j)
                bf[j] = *(const bf16x8*)(Bs + (wn + j * 16 + l15) * 32 + quad * 8);
#pragma unroll
            for (int i = 0; i < 4; ++i)
#pragma unroll
                for (int j = 0; j < 4; ++j)
                    acc[i][j] = __builtin_amdgcn_mfma_f32_16x16x32_bf16(af[i], bf[j], acc[i][j], 0, 0, 0);
            __syncthreads();
        }
    }

    float* oF = p.outF ? p.outF + bz * p.sF : nullptr;
    unsigned short* oH = p.outH ? p.outH + bz * p.sH : nullptr;
    const float* dT = p.dotT ? p.dotT + bz * p.sDot : nullptr;
    float bcol[4];
#pragma unroll
    for (int j = 0; j < 4; ++j)
        bcol[j] = p.bias ? p.bias[colBase + wn + j * 16 + l15] : 0.0f;
    const float* rs = p.rowscale ? p.rowscale + bz * p.sRS : nullptr;
    float dacc = 0.f;
#pragma unroll
    for (int i = 0; i < 4; ++i) {
#pragma unroll
        for (int r = 0; r < 4; ++r) {
            int row = rowBase + wm + i * 16 + quad * 4 + r;
            float sc = rs ? rs[row] : 1.0f;
            long long ro = (long long)row * p.ldc;
#pragma unroll
            for (int j = 0; j < 4; ++j) {
                int col = colBase + wn + j * 16 + l15;
                float v = (acc[i][j][r] + bcol[j]) * sc;
                if (oF) oF[ro + col] = v;
                if (oH) oH[ro + col] = f2b(v);
                if (dT) dacc = fmaf(v, dT[(long long)col * p.ldc + row], dacc);
            }
        }
    }
    if (p.dot_part) {
        dred[tid] = dacc;
        __syncthreads();
        for (int k = 128; k > 0; k >>= 1) {
            if (tid < k) dred[tid] += dred[tid + k];
            __syncthreads();
        }
        if (tid == 0)
            p.dot_part[((long long)bz * gridDim.y + blockIdx.y) * gridDim.x + blockIdx.x] = dred[0];
    }
}

// ---------------------------------------------------------------------------
// G = sT · sT^T via MFMA; writes G bf16 and reduces ssq = sum(G^2), tr = trace
// partials per block (clu closed form + link ssq term).
__global__ __launch_bounds__(256) void sts_clu_mfma(
    const unsigned short* __restrict__ sT, unsigned short* __restrict__ gout,
    float* __restrict__ ssq_part, float* __restrict__ tr_part) {
    __shared__ short As[128 * 32];
    __shared__ short Bs[128 * 32];
    __shared__ float red[2][256];
    const int tid = threadIdx.x;
    const int wave = tid >> 6, lane = tid & 63;
    const int quad = lane >> 4, l15 = lane & 15;
    const int wm = (wave & 1) * 64, wn = (wave >> 1) * 64;
    const long long bz = blockIdx.z;
    const unsigned short* S = sT + bz * 262144;
    const int rowBase = blockIdx.y * 128, colBase = blockIdx.x * 128;
    const int srow = tid >> 2, skg = (tid & 3) * 8;

    f32x4 acc[4][4] = {{{0.f}}};
    const unsigned short* Ab0 = S + (long long)(rowBase + srow) * 1024 + skg;
    const unsigned short* Ab1 = S + (long long)(rowBase + 64 + srow) * 1024 + skg;
    const unsigned short* Bb0 = S + (long long)(colBase + srow) * 1024 + skg;
    const unsigned short* Bb1 = S + (long long)(colBase + 64 + srow) * 1024 + skg;
    for (int k0 = 0; k0 < 1024; k0 += 32) {
        gl_lds16(Ab0 + k0, (char*)As + wave * 1024);
        gl_lds16(Ab1 + k0, (char*)As + 4096 + wave * 1024);
        gl_lds16(Bb0 + k0, (char*)Bs + wave * 1024);
        gl_lds16(Bb1 + k0, (char*)Bs + 4096 + wave * 1024);
        __syncthreads();
        bf16x8 af[4], bf[4];
#pragma unroll
        for (int i = 0; i < 4; ++i)
            af[i] = *(const bf16x8*)(As + (wm + i * 16 + l15) * 32 + quad * 8);
#pragma unroll
        for (int j = 0; j < 4; ++j)
            bf[j] = *(const bf16x8*)(Bs + (wn + j * 16 + l15) * 32 + quad * 8);
#pragma unroll
        for (int i = 0; i < 4; ++i)
#pragma unroll
            for (int j = 0; j < 4; ++j)
                acc[i][j] = __builtin_amdgcn_mfma_f32_16x16x32_bf16(af[i], bf[j], acc[i][j], 0, 0, 0);
        __syncthreads();
    }
    unsigned short* go = gout + bz * 65536;
    float ssq = 0.f, tr = 0.f;
#pragma unroll
    for (int i = 0; i < 4; ++i)
#pragma unroll
        for (int r = 0; r < 4; ++r) {
            int row = rowBase + wm + i * 16 + quad * 4 + r;
#pragma unroll
            for (int j = 0; j < 4; ++j) {
                int col = colBase + wn + j * 16 + l15;
                float v = acc[i][j][r];
                go[(long long)row * 256 + col] = f2b(v);
                ssq = fmaf(v, v, ssq);
                if (row == col) tr += v;
            }
        }
    red[0][tid] = ssq;
    red[1][tid] = tr;
    __syncthreads();
    for (int k = 128; k > 0; k >>= 1) {
        if (tid < k) {
            red[0][tid] += red[0][tid + k];
            red[1][tid] += red[1][tid + k];
        }
        __syncthreads();
    }
    if (tid == 0) {
        int bid = (int)(blockIdx.z * 4 + blockIdx.y * 2 + blockIdx.x);
        ssq_part[bid] = red[0][0];
        tr_part[bid] = red[1][0];
    }
}

// ---------------------------------------------------------------------------
// bf16 elementwise dot over 8,388,608 elems -> per-block partials [1024]
__global__ __launch_bounds__(256) void dot_bf_kernel(const unsigned short* __restrict__ a,
                                                     const unsigned short* __restrict__ b,
                                                     float* __restrict__ part) {
    __shared__ float red[256];
    int tid = threadIdx.x;
    long long base = (long long)blockIdx.x * 8192;
    float acc = 0.f;
#pragma unroll
    for (int i = 0; i < 8; ++i) {
        long long off = base + i * 1024 + tid * 4;
        ushort4 va = *(const ushort4*)(a + off);
        ushort4 vb = *(const ushort4*)(b + off);
        acc = fmaf(b2f(va.x), b2f(vb.x), acc);
        acc = fmaf(b2f(va.y), b2f(vb.y), acc);
        acc = fmaf(b2f(va.z), b2f(vb.z), acc);
        acc = fmaf(b2f(va.w), b2f(vb.w), acc);
    }
    red[tid] = acc;
    __syncthreads();
    for (int k = 128; k > 0; k >>= 1) {
        if (tid < k) red[tid] += red[tid + k];
        __syncthreads();
    }
    if (tid == 0) part[blockIdx.x] = red[0];
}

// ---------------------------------------------------------------------------
// l2-normalize each 256-wide row then relu; bf16, in-place.
__global__ __launch_bounds__(256) void l2relu_bf_kernel(unsigned short* __restrict__ buf) {
    __shared__ float red[256];
    long long row = blockIdx.x;
    int tid = threadIdx.x;
    float v = b2f(buf[row * 256 + tid]);
    red[tid] = v * v;
    __syncthreads();
    for (int k = 128; k > 0; k >>= 1) {
        if (tid < k) red[tid] += red[tid + k];
        __syncthreads();
    }
    float rn = 1.0f / fmaxf(sqrtf(red[0]), 1e-12f);
    buf[row * 256 + tid] = f2b(fmaxf(v * rn, 0.0f));
}

__global__ __launch_bounds__(256) void softmax_kernel(float* __restrict__ s) {
    __shared__ float red[256];
    long long row = blockIdx.x;
    int tid = threadIdx.x;
    float v = s[row * 256 + tid];
    red[tid] = v;
    __syncthreads();
    for (int k = 128; k > 0; k >>= 1) {
        if (tid < k) red[tid] = fmaxf(red[tid], red[tid + k]);
        __syncthreads();
    }
    float m = red[0];
    __syncthreads();
    float e = expf(v - m);
    red[tid] = e;
    __syncthreads();
    for (int k = 128; k > 0; k >>= 1) {
        if (tid < k) red[tid] += red[tid + k];
        __syncthreads();
    }
    s[row * 256 + tid] = e / red[0];
}

// scores[b,c] = sum_n s[b,n,c]
__global__ __launch_bounds__(256) void scores_kernel(const float* __restrict__ s,
                                                     float* __restrict__ scores) {
    int b = blockIdx.x, chunk = blockIdx.y, c = threadIdx.x;
    const float* base = s + (long long)b * 262144 + (long long)chunk * 32 * 256 + c;
    float acc = 0.f;
#pragma unroll
    for (int i = 0; i < 32; ++i) acc += base[i * 256];
    atomicAdd(&scores[b * 256 + c], acc);
}

__global__ __launch_bounds__(256) void topk_kernel(const float* __restrict__ scores,
                                                   float* __restrict__ thresh) {
    __shared__ float vals[256];
    int b = blockIdx.x, tid = threadIdx.x;
    float v = scores[b * 256 + tid];
    vals[tid] = v;
    __syncthreads();
    int rank = 0;
    for (int j = 0; j < 256; ++j) {
        float u = vals[j];
        rank += (u > v) || (u == v && j < tid);
    }
    if (rank == 127) thresh[b] = v;
}

__global__ __launch_bounds__(256) void gate_kernel(const float* __restrict__ scores,
                                                   const float* __restrict__ thresh,
                                                   float* __restrict__ gate) {
    int b = blockIdx.x, c = threadIdx.x;
    float z = (scores[b * 256 + c] - thresh[b]) * 10.0f;  // 1/TEMP
    gate[b * 256 + c] = 1.0f / (1.0f + expf(-z));
}

// s *= gate (fp32, in place) + bf16 copy + entropy partials
__global__ __launch_bounds__(256) void gate_ent_kernel(float* __restrict__ s,
                                                       const float* __restrict__ gate,
                                                       unsigned short* __restrict__ sbf,
                                                       float* __restrict__ ent_part) {
    __shared__ float red[256];
    int tid = threadIdx.x;
    long long row = blockIdx.x;
    int b = blockIdx.x >> 10;
    float v = s[row * 256 + tid] * gate[b * 256 + tid];
    s[row * 256 + tid] = v;
    sbf[row * 256 + tid] = f2b(v);
    red[tid] = -v * logf(v + 1e-15f);
    __syncthreads();
    for (int k = 128; k > 0; k >>= 1) {
        if (tid < k) red[tid] += red[tid + k];
        __syncthreads();
    }
    if (tid == 0) ent_part[blockIdx.x] = red[0];
}

// ---------------------------------------------------------------------------
__global__ __launch_bounds__(256) void finalize_kernel(const float* __restrict__ ent_part,
                                                       const float* __restrict__ asq_part,
                                                       const float* __restrict__ psq_part,
                                                       const float* __restrict__ sdot_part,
                                                       const float* __restrict__ trq_part,
                                                       const float* __restrict__ ssq_part,
                                                       const float* __restrict__ tr_part,
                                                       float* __restrict__ scal) {
    __shared__ float red[7][256];
    int tid = threadIdx.x;
    float e = 0.f, asq = 0.f, psq = 0.f, sd = 0.f, tq = 0.f, clu = 0.f, ssqa = 0.f;
    for (int i = tid; i < 32768; i += 256) e += ent_part[i];
    for (int i = tid; i < 8192; i += 256) asq += asq_part[i];
    for (int i = tid; i < 512; i += 256) psq += psq_part[i];
    for (int i = tid; i < 1024; i += 256) sd += sdot_part[i];
    if (tid < 128) tq = trq_part[tid];
    if (tid < 32) {
        float ssq = 0.f, tr = 0.f;
#pragma unroll
        for (int i = 0; i < 4; ++i) {
            ssq += ssq_part[tid * 4 + i];
            tr  += tr_part[tid * 4 + i];
        }
        ssqa = ssq;
        float fro = fmaxf(sqrtf(ssq), 1e-12f);
        float val = ssq / (fro * fro) - tr / (8.0f * fro) + 1.0f;  // ||G/fro - I/16||_F^2
        clu = sqrtf(fmaxf(val, 0.0f));
    }
    red[0][tid] = e; red[1][tid] = asq; red[2][tid] = psq; red[3][tid] = sd;
    red[4][tid] = tq; red[5][tid] = clu; red[6][tid] = ssqa;
    __syncthreads();
    for (int k = 128; k > 0; k >>= 1) {
        if (tid < k) {
#pragma unroll
            for (int q = 0; q < 7; ++q) red[q][tid] += red[q][tid + k];
        }
        __syncthreads();
    }
    if (tid == 0) {
        const float numel = 33554432.0f;  // B*N*N
        float linksq  = red[1][0] - 2.0f * red[3][0] + red[6][0];   // asq - 2<S,AS> + ||G||^2
        float reconsq = red[1][0] - 2.0f * red[2][0] + red[4][0];   // asq - 2||P||^2 + tr(GP'GP)
        scal[0] = sqrtf(fmaxf(linksq, 0.0f)) / numel;   // link
        scal[1] = red[0][0] / 32768.0f;                 // ent
        scal[2] = red[5][0] / 32.0f;                    // clu
        scal[3] = sqrtf(fmaxf(reconsq, 0.0f)) / numel;  // recon
    }
}

// ---------------------------------------------------------------------------
extern "C" void kernel_launch(void* const* d_in, const int* in_sizes, int n_in,
                              void* d_out, int out_size, void* d_ws, size_t ws_size,
                              hipStream_t stream) {
    const float* x    = (const float*)d_in[0];
    const float* adj  = (const float*)d_in[1];
    const float* Wr_p = (const float*)d_in[2];
    const float* br_p = (const float*)d_in[3];
    const float* Wo_p = (const float*)d_in[4];
    const float* Wl_p = (const float*)d_in[5];
    const float* bl_p = (const float*)d_in[6];
    const float* Wr_e = (const float*)d_in[7];
    const float* br_e = (const float*)d_in[8];
    const float* Wo_e = (const float*)d_in[9];
    const float* Wl_e = (const float*)d_in[10];
    const float* bl_e = (const float*)d_in[11];

    float* out    = (float*)d_out;
    float* xp     = out;              // [32,256,256]
    float* adj_p  = out + 2097152;    // [32,256,256]
    float* s      = out + 4194304;    // [32,1024,256] fp32
    float* scal   = out + 12582912;
    float* node_x = out + 12582916;   // [32,1024,256] fp32

    char* w = (char*)d_ws;
    float* degsum     = (float*)w; w += 32768 * 4;
    float* scores     = (float*)w; w += 8192 * 4;
    float* thresh     = (float*)w; w += 256 * 4;
    float* gatep      = (float*)w; w += 8192 * 4;
    float* ent_part   = (float*)w; w += 32768 * 4;
    float* asq_part   = (float*)w; w += 8192 * 4;
    float* psq_part   = (float*)w; w += 512 * 4;
    float* sdot_part  = (float*)w; w += 1024 * 4;
    float* trq_part   = (float*)w; w += 256 * 4;
    float* ssq_part   = (float*)w; w += 256 * 4;
    float* tr_part    = (float*)w; w += 256 * 4;
    unsigned short* WT   = (unsigned short*)w; w += 6LL * 65536 * 2;
    unsigned short* bufA = (unsigned short*)w; w += 33554432LL * 2;  // adj_bf
    unsigned short* bufB = (unsigned short*)w; w += 8388608LL * 2;   // x_bf -> {G_bf, PT_bf, M1}
    unsigned short* bufC = (unsigned short*)w; w += 8388608LL * 2;   // xT_bf -> sT_bf
    unsigned short* bufD = (unsigned short*)w; w += 8388608LL * 2;   // agg_bf -> nxT_bf
    unsigned short* bufE = (unsigned short*)w; w += 8388608LL * 2;   // h_bf -> aTs_bf
    unsigned short* bufF = (unsigned short*)w; w += 8388608LL * 2;   // aTsT_bf
    unsigned short* bufG = (unsigned short*)w; w += 8388608LL * 2;   // s_bf
    unsigned short* bufH = (unsigned short*)w; w += 2097152LL * 2;   // P_bf

    unsigned short* G_bf  = bufB;                        // [32,256,256] bf16 (after x_bf dead)
    unsigned short* PT_bf = bufB + 2097152;              // [32,256,256] bf16
    float*          M1    = (float*)(bufB + 4194304);    // [32,256,256] fp32

    hipMemsetAsync(degsum, 0, (32768 + 8192) * sizeof(float), stream);

    // 1) adj -> adj_bf + deg row sums + sum(adj^2) partials (single adj pass)
    convt_kernel<<<dim3(16, 16, 32), 256, 0, stream>>>(
        adj, 1048576LL, 1024, bufA, 1048576LL, nullptr, 0, 0, degsum, 1024LL, asq_part);
    recip_kernel<<<128, 256, 0, stream>>>(degsum);

    // 2) x -> x_bf + xT_bf
    convt_kernel<<<dim3(4, 16, 32), 256, 0, stream>>>(
        x, 262144LL, 256, bufB, 262144LL, bufC, 262144LL, 1024, nullptr, 0, nullptr);

    // 3) weights -> transposed bf16
    WPtrs wp;
    wp.in[0] = Wr_p; wp.in[1] = Wo_p; wp.in[2] = Wl_p;
    wp.in[3] = Wr_e; wp.in[4] = Wo_e; wp.in[5] = Wl_e;
    for (int i = 0; i < 6; ++i) wp.out[i] = WT + (long long)i * 65536;
    wconv_kernel<<<dim3(4, 4, 6), 256, 0, stream>>>(wp);

    GemmP g;
    // 4) agg = (adj @ x) * deg -> agg_bf (bufD)
    g = {};
    g.A1 = bufA; g.sA1 = 1048576; g.lda1 = 1024; g.K1 = 1024;
    g.B1 = bufC; g.sB1 = 262144; g.ldb1 = 1024;
    g.outH = bufD; g.sH = 262144; g.ldc = 256;
    g.rowscale = degsum; g.sRS = 1024;
    gemm_mfma<<<dim3(2, 8, 32), 256, 0, stream>>>(g);

    // 5) pool pre-norm: h = agg@Wr_p + x@Wo_p + br_p -> bufE; l2relu in place
    g = {};
    g.A1 = bufD; g.sA1 = 0; g.lda1 = 256; g.K1 = 256; g.B1 = WT + 0 * 65536; g.sB1 = 0; g.ldb1 = 256;
    g.A2 = bufB; g.sA2 = 0; g.lda2 = 256; g.K2 = 256; g.B2 = WT + 1 * 65536; g.sB2 = 0; g.ldb2 = 256;
    g.outH = bufE; g.sH = 0; g.ldc = 256; g.bias = br_p;
    gemm_mfma<<<dim3(2, 256, 1), 256, 0, stream>>>(g);
    l2relu_bf_kernel<<<32768, 256, 0, stream>>>(bufE);

    // 6) s_logits = h @ Wl_p + bl_p -> s (fp32)
    g = {};
    g.A1 = bufE; g.sA1 = 0; g.lda1 = 256; g.K1 = 256; g.B1 = WT + 2 * 65536; g.sB1 = 0; g.ldb1 = 256;
    g.outF = s; g.sF = 0; g.ldc = 256; g.bias = bl_p;
    gemm_mfma<<<dim3(2, 256, 1), 256, 0, stream>>>(g);

    // 7) embed branch (reuses bufE)
    g = {};
    g.A1 = bufD; g.sA1 = 0; g.lda1 = 256; g.K1 = 256; g.B1 = WT + 3 * 65536; g.sB1 = 0; g.ldb1 = 256;
    g.A2 = bufB; g.sA2 = 0; g.lda2 = 256; g.K2 = 256; g.B2 = WT + 4 * 65536; g.sB2 = 0; g.ldb2 = 256;
    g.outH = bufE; g.sH = 0; g.ldc = 256; g.bias = br_e;
    gemm_mfma<<<dim3(2, 256, 1), 256, 0, stream>>>(g);
    l2relu_bf_kernel<<<32768, 256, 0, stream>>>(bufE);
    g = {};
    g.A1 = bufE; g.sA1 = 0; g.lda1 = 256; g.K1 = 256; g.B1 = WT + 5 * 65536; g.sB1 = 0; g.ldb1 = 256;
    g.outF = node_x; g.sF = 0; g.ldc = 256; g.bias = bl_e;
    gemm_mfma<<<dim3(2, 256, 1), 256, 0, stream>>>(g);

    // 8) softmax, scores, topk, gate, apply+entropy (+s_bf in bufG)
    softmax_kernel<<<32768, 256, 0, stream>>>(s);
    scores_kernel<<<dim3(32, 32, 1), 256, 0, stream>>>(s, scores);
    topk_kernel<<<32, 256, 0, stream>>>(scores, thresh);
    gate_kernel<<<32, 256, 0, stream>>>(scores, thresh, gatep);
    gate_ent_kernel<<<32768, 256, 0, stream>>>(s, gatep, bufG, ent_part);

    // 9) transposes: s -> sT_bf (bufC), node_x -> nxT_bf (bufD)
    convt_kernel<<<dim3(4, 16, 32), 256, 0, stream>>>(
        s, 262144LL, 256, nullptr, 0, bufC, 262144LL, 1024, nullptr, 0, nullptr);
    convt_kernel<<<dim3(4, 16, 32), 256, 0, stream>>>(
        node_x, 262144LL, 256, nullptr, 0, bufD, 262144LL, 1024, nullptr, 0, nullptr);

    // 10) xp = sT · nxT^T (fp32 out)
    g = {};
    g.A1 = bufC; g.sA1 = 262144; g.lda1 = 1024; g.K1 = 1024;
    g.B1 = bufD; g.sB1 = 262144; g.ldb1 = 1024;
    g.outF = xp; g.sF = 65536; g.ldc = 256;
    gemm_mfma<<<dim3(2, 2, 32), 256, 0, stream>>>(g);

    // 11) aTs = adj · s -> bufE bf16 [1024,256]
    g = {};
    g.A1 = bufA; g.sA1 = 1048576; g.lda1 = 1024; g.K1 = 1024;
    g.B1 = bufC; g.sB1 = 262144; g.ldb1 = 1024;
    g.outH = bufE; g.sH = 262144; g.ldc = 256;
    gemm_mfma<<<dim3(2, 8, 32), 256, 0, stream>>>(g);

    // 12) aTs -> aTsT_bf (bufF, [256,1024])
    tbf16_kernel<<<dim3(4, 16, 32), 256, 0, stream>>>(
        bufE, 262144LL, 256, bufF, 262144LL, 1024);

    // 13) G = sT·sT^T -> G_bf + ssq/tr partials (clu & link terms)
    sts_clu_mfma<<<dim3(2, 2, 32), 256, 0, stream>>>(bufC, G_bf, ssq_part, tr_part);

    // 14) adj_p = sT · aTsT^T (fp32 out)  [= S^T (A S)]
    g = {};
    g.A1 = bufC; g.sA1 = 262144; g.lda1 = 1024; g.K1 = 1024;
    g.B1 = bufF; g.sB1 = 262144; g.ldb1 = 1024;
    g.outF = adj_p; g.sF = 65536; g.ldc = 256;
    gemm_mfma<<<dim3(2, 2, 32), 256, 0, stream>>>(g);

    // 15) adj_p -> P_bf (bufH) + PT_bf + ||P||^2 partials
    convt_kernel<<<dim3(4, 4, 32), 256, 0, stream>>>(
        adj_p, 65536LL, 256, bufH, 65536LL, PT_bf, 65536LL, 256, nullptr, 0, psq_part);

    // 16) sdot = <S, A·S> partials (link cross term)
    dot_bf_kernel<<<1024, 256, 0, stream>>>(bufG, bufE, sdot_part);

    // 17) M1 = G · P (fp32 out)
    g = {};
    g.A1 = G_bf; g.sA1 = 65536; g.lda1 = 256; g.K1 = 256;
    g.B1 = PT_bf; g.sB1 = 65536; g.ldb1 = 256;
    g.outF = M1; g.sF = 65536; g.ldc = 256;
    gemm_mfma<<<dim3(2, 2, 32), 256, 0, stream>>>(g);

    // 18) M2 = G · P^T with trace-dot vs M1: trq = sum M2_ij * M1_ji
    g = {};
    g.A1 = G_bf; g.sA1 = 65536; g.lda1 = 256; g.K1 = 256;
    g.B1 = bufH; g.sB1 = 65536; g.ldb1 = 256;
    g.ldc = 256;
    g.dotT = M1; g.sDot = 65536; g.dot_part = trq_part;
    gemm_mfma<<<dim3(2, 2, 32), 256, 0, stream>>>(g);

    // 19) finalize
    finalize_kernel<<<1, 256, 0, stream>>>(ent_part, asq_part, psq_part, sdot_part,
                                           trq_part, ssq_part, tr_part, scal);
}